// Round 1
// baseline (2458.840 us; speedup 1.0000x reference)
//
#include <hip/hip_runtime.h>
#include <math.h>

// Problem dims (match reference)
#define B_    128
#define T_    250
#define IN_   700
#define H_    512
#define OUT_  20
#define BR_   4
#define HB_   2048   // H_*BR_
#define TC_   50     // time chunk for cur staging buffer
#define WARM_ 10
#define VTH_  1.0f

// ---------------- elementwise helpers ----------------
__global__ void mask_mul_kernel(const float* __restrict__ w, const float* __restrict__ m,
                                float* __restrict__ out, int n4) {
    int i = blockIdx.x * blockDim.x + threadIdx.x;
    if (i < n4) {
        float4 a = ((const float4*)w)[i];
        float4 b = ((const float4*)m)[i];
        float4 c;
        c.x = a.x * b.x; c.y = a.y * b.y; c.z = a.z * b.z; c.w = a.w * b.w;
        ((float4*)out)[i] = c;
    }
}

__global__ void zero_kernel(float* __restrict__ p, int n4) {
    int i = blockIdx.x * blockDim.x + threadIdx.x;
    if (i < n4) ((float4*)p)[i] = make_float4(0.f, 0.f, 0.f, 0.f);
}

// ---------------- fp32 tiled GEMM:  C[m,n] = A[m,:] . B[n,:] + bias[n] ----------------
// A rows are time-chunk mapped: local row r -> global row (r/Tc)*T_ + t0 + (r%Tc)
#define BM 64
#define BN 64
#define BK 16

__global__ __launch_bounds__(256)
void gemm_bt_kernel(const float* __restrict__ A, const float* __restrict__ Bm,
                    const float* __restrict__ bias, float* __restrict__ C,
                    int Mloc, int N, int K, int Tc, int t0) {
    __shared__ float As[BK][BM + 4];
    __shared__ float Bs[BK][BN + 4];
    const int tx = threadIdx.x;           // 0..15
    const int ty = threadIdx.y;           // 0..15
    const int tid = ty * 16 + tx;
    const int bm = blockIdx.y * BM;
    const int bn = blockIdx.x * BN;

    const int lr = tid >> 2;              // 0..63 : row within tile
    const int lk = (tid & 3) << 2;        // 0,4,8,12 : k offset

    // A row mapping (chunk-local -> global)
    const int r = bm + lr;
    const int bb = r / Tc;
    const int tl = r - bb * Tc;
    const float* Arow = A + ((size_t)bb * T_ + t0 + tl) * (size_t)K;

    const int nr = bn + lr;
    const bool nvld = (nr < N);
    const float* Brow = Bm + (size_t)(nvld ? nr : 0) * (size_t)K;

    float acc[4][4];
#pragma unroll
    for (int i = 0; i < 4; i++)
#pragma unroll
        for (int j = 0; j < 4; j++) acc[i][j] = 0.f;

    for (int k0 = 0; k0 < K; k0 += BK) {
        float4 av, bv;
        if (k0 + lk + 3 < K) {
            av = *(const float4*)(Arow + k0 + lk);
        } else {
            av.x = (k0 + lk + 0 < K) ? Arow[k0 + lk + 0] : 0.f;
            av.y = (k0 + lk + 1 < K) ? Arow[k0 + lk + 1] : 0.f;
            av.z = (k0 + lk + 2 < K) ? Arow[k0 + lk + 2] : 0.f;
            av.w = (k0 + lk + 3 < K) ? Arow[k0 + lk + 3] : 0.f;
        }
        if (nvld) {
            if (k0 + lk + 3 < K) {
                bv = *(const float4*)(Brow + k0 + lk);
            } else {
                bv.x = (k0 + lk + 0 < K) ? Brow[k0 + lk + 0] : 0.f;
                bv.y = (k0 + lk + 1 < K) ? Brow[k0 + lk + 1] : 0.f;
                bv.z = (k0 + lk + 2 < K) ? Brow[k0 + lk + 2] : 0.f;
                bv.w = (k0 + lk + 3 < K) ? Brow[k0 + lk + 3] : 0.f;
            }
        } else {
            bv = make_float4(0.f, 0.f, 0.f, 0.f);
        }
        As[lk + 0][lr] = av.x; As[lk + 1][lr] = av.y;
        As[lk + 2][lr] = av.z; As[lk + 3][lr] = av.w;
        Bs[lk + 0][lr] = bv.x; Bs[lk + 1][lr] = bv.y;
        Bs[lk + 2][lr] = bv.z; Bs[lk + 3][lr] = bv.w;
        __syncthreads();

#pragma unroll
        for (int k = 0; k < BK; k++) {
            float4 a4 = *(const float4*)&As[k][ty * 4];
            float4 b4 = *(const float4*)&Bs[k][tx * 4];
            acc[0][0] += a4.x * b4.x; acc[0][1] += a4.x * b4.y;
            acc[0][2] += a4.x * b4.z; acc[0][3] += a4.x * b4.w;
            acc[1][0] += a4.y * b4.x; acc[1][1] += a4.y * b4.y;
            acc[1][2] += a4.y * b4.z; acc[1][3] += a4.y * b4.w;
            acc[2][0] += a4.z * b4.x; acc[2][1] += a4.z * b4.y;
            acc[2][2] += a4.z * b4.z; acc[2][3] += a4.z * b4.w;
            acc[3][0] += a4.w * b4.x; acc[3][1] += a4.w * b4.y;
            acc[3][2] += a4.w * b4.z; acc[3][3] += a4.w * b4.w;
        }
        __syncthreads();
    }

#pragma unroll
    for (int i = 0; i < 4; i++) {
        int m_ = bm + ty * 4 + i;
        if (m_ < Mloc) {
#pragma unroll
            for (int j = 0; j < 4; j++) {
                int n_ = bn + tx * 4 + j;
                if (n_ < N) C[(size_t)m_ * N + n_] = acc[i][j] + bias[n_];
            }
        }
    }
}

// ---------------- per-(b,h) LIF scan over a time chunk ----------------
// cur: chunk-local [B*TC_, HB_]; states persist in ws across chunks.
__global__ __launch_bounds__(256)
void scan_kernel(const float* __restrict__ cur, float* __restrict__ dst,
                 float* __restrict__ mst, float* __restrict__ spst,
                 float* __restrict__ sout, const float* __restrict__ tau_m,
                 const float* __restrict__ tau_n, int t0) {
    int idx = blockIdx.x * 256 + threadIdx.x;  // b*H + h, exactly B_*H_ threads
    int b = idx >> 9;
    int h = idx & (H_ - 1);

    float alpha = 1.f / (1.f + expf(-tau_m[h]));
    float4 tn = ((const float4*)tau_n)[h];
    float4 beta;
    beta.x = 1.f / (1.f + expf(-tn.x));
    beta.y = 1.f / (1.f + expf(-tn.y));
    beta.z = 1.f / (1.f + expf(-tn.z));
    beta.w = 1.f / (1.f + expf(-tn.w));

    float4 d = ((const float4*)dst)[idx];
    float m = mst[idx];
    float sp = spst[idx];

    const float* cp = cur + (size_t)b * TC_ * HB_ + h * BR_;
    float* so = sout + ((size_t)b * T_ + t0) * H_ + h;

    for (int t = 0; t < TC_; t++) {
        float4 c = *(const float4*)cp;
        cp += HB_;
        d.x = beta.x * d.x + (1.f - beta.x) * c.x;
        d.y = beta.y * d.y + (1.f - beta.y) * c.y;
        d.z = beta.z * d.z + (1.f - beta.z) * c.z;
        d.w = beta.w * d.w + (1.f - beta.w) * c.w;
        float s4 = ((d.x + d.y) + d.z) + d.w;
        m = m * alpha + (1.f - alpha) * s4 - VTH_ * sp;
        sp = (m > VTH_) ? 1.f : 0.f;
        *so = sp;
        so += H_;
    }

    ((float4*)dst)[idx] = d;
    mst[idx] = m;
    spst[idx] = sp;
}

// ---------------- readout: leaky integrator + per-step softmax + sum ----------------
__global__ __launch_bounds__(64)
void readout_kernel(const float* __restrict__ curo, const float* __restrict__ tau_mo,
                    float* __restrict__ out) {
    int b = blockIdx.x;
    int o = threadIdx.x;            // one wave; lanes 0..19 active
    bool act = (o < OUT_);
    float ao = 1.f / (1.f + expf(-tau_mo[act ? o : 0]));
    float mo = 0.f, accv = 0.f;
    const float* cp = curo + (size_t)b * T_ * OUT_;
    for (int t = 0; t < T_; t++) {
        float c = act ? cp[t * OUT_ + o] : 0.f;
        mo = mo * ao + (1.f - ao) * c;
        float v = act ? mo : -3.0e38f;
#pragma unroll
        for (int s = 16; s > 0; s >>= 1) v = fmaxf(v, __shfl_xor(v, s, 32));
        float e = act ? expf(mo - v) : 0.f;
        float se = e;
#pragma unroll
        for (int s = 16; s > 0; s >>= 1) se += __shfl_xor(se, s, 32);
        if (t >= WARM_ + 1) accv += e / se;
    }
    if (act) out[b * OUT_ + o] = accv;
}

extern "C" void kernel_launch(void* const* d_in, const int* in_sizes, int n_in,
                              void* d_out, int out_size, void* d_ws, size_t ws_size,
                              hipStream_t stream) {
    const float* x      = (const float*)d_in[0];
    const float* W1     = (const float*)d_in[1];
    const float* b1     = (const float*)d_in[2];
    const float* tau_m1 = (const float*)d_in[3];
    const float* tau_n1 = (const float*)d_in[4];
    const float* mask1  = (const float*)d_in[5];
    const float* W2     = (const float*)d_in[6];
    const float* b2     = (const float*)d_in[7];
    const float* tau_m2 = (const float*)d_in[8];
    const float* tau_n2 = (const float*)d_in[9];
    const float* mask2  = (const float*)d_in[10];
    const float* Wo     = (const float*)d_in[11];
    const float* bo     = (const float*)d_in[12];
    const float* tau_mo = (const float*)d_in[13];
    float* out = (float*)d_out;

    float* ws = (float*)d_ws;
    size_t off = 0;
    float* Wm1  = ws + off; off += (size_t)HB_ * IN_;        // 2048*700
    float* Wm2  = ws + off; off += (size_t)HB_ * H_;         // 2048*512
    float* s1   = ws + off; off += (size_t)B_ * T_ * H_;     // spikes layer1
    float* s2   = ws + off; off += (size_t)B_ * T_ * H_;     // spikes layer2
    float* curo = ws + off; off += (size_t)B_ * T_ * OUT_;
    float* st   = ws + off;                                  // states block start
    float* d1   = ws + off; off += (size_t)B_ * H_ * BR_;
    float* m1   = ws + off; off += (size_t)B_ * H_;
    float* sp1  = ws + off; off += (size_t)B_ * H_;
    float* d2   = ws + off; off += (size_t)B_ * H_ * BR_;
    float* m2   = ws + off; off += (size_t)B_ * H_;
    float* sp2  = ws + off; off += (size_t)B_ * H_;
    size_t stf  = (size_t)(ws + off - st);                   // state floats (786432)
    float* cur  = ws + off; off += (size_t)B_ * TC_ * HB_;   // chunk staging

    // Prep: masked weights + zero states (ws is re-poisoned before every call)
    int n4a = HB_ * IN_ / 4;
    mask_mul_kernel<<<(n4a + 255) / 256, 256, 0, stream>>>(W1, mask1, Wm1, n4a);
    int n4b = HB_ * H_ / 4;
    mask_mul_kernel<<<(n4b + 255) / 256, 256, 0, stream>>>(W2, mask2, Wm2, n4b);
    int n4z = (int)(stf / 4);
    zero_kernel<<<(n4z + 255) / 256, 256, 0, stream>>>(st, n4z);

    dim3 blk(16, 16);
    const int NCH = T_ / TC_;
    // Layer 1: chunked GEMM + scan
    for (int c = 0; c < NCH; c++) {
        dim3 g1(HB_ / BN, (B_ * TC_) / BM);
        gemm_bt_kernel<<<g1, blk, 0, stream>>>(x, Wm1, b1, cur, B_ * TC_, HB_, IN_, TC_, c * TC_);
        scan_kernel<<<B_ * H_ / 256, 256, 0, stream>>>(cur, d1, m1, sp1, s1, tau_m1, tau_n1, c * TC_);
    }
    // Layer 2
    for (int c = 0; c < NCH; c++) {
        dim3 g2(HB_ / BN, (B_ * TC_) / BM);
        gemm_bt_kernel<<<g2, blk, 0, stream>>>(s1, Wm2, b2, cur, B_ * TC_, HB_, H_, TC_, c * TC_);
        scan_kernel<<<B_ * H_ / 256, 256, 0, stream>>>(cur, d2, m2, sp2, s2, tau_m2, tau_n2, c * TC_);
    }
    // Readout GEMM (full M, identity mapping via Tc = T_)
    dim3 g3((OUT_ + BN - 1) / BN, (B_ * T_) / BM);
    gemm_bt_kernel<<<g3, blk, 0, stream>>>(s2, Wo, bo, curo, B_ * T_, OUT_, H_, T_, 0);
    // Readout scan + softmax accumulation
    readout_kernel<<<B_, 64, 0, stream>>>(curo, tau_mo, out);
}

// Round 2
// 1568.834 us; speedup vs baseline: 1.5673x; 1.5673x over previous
//
#include <hip/hip_runtime.h>
#include <math.h>

// Problem dims
#define B_    128
#define T_    250
#define IN_   700
#define INP_  704    // padded to 32
#define H_    512
#define OUT_  20
#define BR_   4
#define HB_   2048   // H_*BR_
#define TC_   50     // time chunk
#define MCH_  6400   // B_*TC_ rows per chunk
#define WARM_ 10
#define VTH_  1.0f

typedef __attribute__((ext_vector_type(8))) _Float16 half8;
typedef __attribute__((ext_vector_type(4))) float f32x4;
typedef const __attribute__((address_space(1))) void* gptr_t;
typedef __attribute__((address_space(3))) void* lptr_t;

struct Segs { const _Float16* a[3]; const _Float16* w[3]; };

// ---------------- prep: split fp32 -> hi/lo fp16 planes ----------------
__global__ __launch_bounds__(256)
void w1prep_kernel(const float* __restrict__ W, const float* __restrict__ M,
                   _Float16* __restrict__ w0, _Float16* __restrict__ w1) {
    int i = blockIdx.x * 256 + threadIdx.x;           // over HB_*INP_
    if (i >= HB_ * INP_) return;
    int r = i / INP_, c = i - r * INP_;
    float v = (c < IN_) ? W[(size_t)r * IN_ + c] * M[(size_t)r * IN_ + c] : 0.f;
    _Float16 h0 = (_Float16)v;
    w0[i] = h0;
    w1[i] = (_Float16)(v - (float)h0);
}

__global__ __launch_bounds__(256)
void w2prep_kernel(const float* __restrict__ W, const float* __restrict__ M,
                   _Float16* __restrict__ w0, _Float16* __restrict__ w1,
                   _Float16* __restrict__ w2) {
    int i = blockIdx.x * 256 + threadIdx.x;           // over HB_*H_
    if (i >= HB_ * H_) return;
    float v = W[i] * M[i];
    _Float16 h0 = (_Float16)v;
    float r1 = v - (float)h0;
    _Float16 h1 = (_Float16)r1;
    float r2 = r1 - (float)h1;
    w0[i] = h0; w1[i] = h1; w2[i] = (_Float16)r2;
}

// per-chunk x conversion: global rows (bb*T_+t0+tl) -> chunk-local [MCH_, INP_]
__global__ __launch_bounds__(256)
void convx_kernel(const float* __restrict__ x, _Float16* __restrict__ x0,
                  _Float16* __restrict__ x1, int t0) {
    int i = blockIdx.x * 256 + threadIdx.x;           // over MCH_*INP_
    if (i >= MCH_ * INP_) return;
    int r = i / INP_, c = i - r * INP_;
    int bb = r / TC_, tl = r - bb * TC_;
    float v = (c < IN_) ? x[((size_t)bb * T_ + t0 + tl) * IN_ + c] : 0.f;
    _Float16 h0 = (_Float16)v;
    x0[i] = h0;
    x1[i] = (_Float16)(v - (float)h0);
}

__global__ void zero_kernel(float* __restrict__ p, int n4) {
    int i = blockIdx.x * blockDim.x + threadIdx.x;
    if (i < n4) ((float4*)p)[i] = make_float4(0.f, 0.f, 0.f, 0.f);
}

// ---------------- segmented-K fp16 MFMA GEMM (m97 structure) ----------------
// C[m,n] = sum_s A_s[m,:] . W_s[n,:]  + bias[n];  M=MCH_ (mult of 128), N mult of 128
__global__ __launch_bounds__(256)
void mfma_gemm_kernel(Segs segs, int ktiles, int ld,
                      const float* __restrict__ bias, float* __restrict__ C, int N) {
    __shared__ alignas(16) _Float16 As[128 * 32];
    __shared__ alignas(16) _Float16 Bs[128 * 32];
    const int tid  = threadIdx.x;
    const int wave = tid >> 6, lane = tid & 63;
    const int bm = blockIdx.y * 128, bn = blockIdx.x * 128;

    // staging: thread covers rows (tid>>2) and (tid>>2)+64, 16B each at k-offset (tid&3)*8
    const int    srow  = tid >> 2;
    const int    skoff = (tid & 3) * 8;
    const size_t aoff0 = (size_t)(bm + srow) * ld + skoff;
    const size_t aoff1 = aoff0 + (size_t)64 * ld;
    const size_t boff0 = (size_t)(bn + srow) * ld + skoff;
    const size_t boff1 = boff0 + (size_t)64 * ld;
    lptr_t lA0 = (lptr_t)(As + wave * 512);
    lptr_t lA1 = (lptr_t)(As + 2048 + wave * 512);
    lptr_t lB0 = (lptr_t)(Bs + wave * 512);
    lptr_t lB1 = (lptr_t)(Bs + 2048 + wave * 512);

    const int wm = wave & 1, wn = wave >> 1;
    const int fr = lane & 15;          // A row / B col within 16-tile
    const int fk = (lane >> 4) * 8;    // k offset (halfs)

    f32x4 acc[4][4] = {};

#pragma unroll
    for (int s = 0; s < 3; s++) {
        const _Float16* pa = segs.a[s];
        const _Float16* pw = segs.w[s];
        for (int kt = 0; kt < ktiles; kt++) {
            const int k0 = kt * 32;
            __builtin_amdgcn_global_load_lds((gptr_t)(pa + aoff0 + k0), lA0, 16, 0, 0);
            __builtin_amdgcn_global_load_lds((gptr_t)(pa + aoff1 + k0), lA1, 16, 0, 0);
            __builtin_amdgcn_global_load_lds((gptr_t)(pw + boff0 + k0), lB0, 16, 0, 0);
            __builtin_amdgcn_global_load_lds((gptr_t)(pw + boff1 + k0), lB1, 16, 0, 0);
            __syncthreads();

            half8 af[4], bf[4];
#pragma unroll
            for (int mi = 0; mi < 4; mi++)
                af[mi] = *(const half8*)&As[(wm * 64 + mi * 16 + fr) * 32 + fk];
#pragma unroll
            for (int ni = 0; ni < 4; ni++)
                bf[ni] = *(const half8*)&Bs[(wn * 64 + ni * 16 + fr) * 32 + fk];
#pragma unroll
            for (int mi = 0; mi < 4; mi++)
#pragma unroll
                for (int ni = 0; ni < 4; ni++)
                    acc[mi][ni] = __builtin_amdgcn_mfma_f32_16x16x32_f16(
                        af[mi], bf[ni], acc[mi][ni], 0, 0, 0);
            __syncthreads();
        }
    }

    // epilogue: C/D layout col=lane&15, row=(lane>>4)*4+reg
    const int cc = lane & 15;
    const int cr = (lane >> 4) * 4;
#pragma unroll
    for (int ni = 0; ni < 4; ni++) {
        const int gc = bn + wn * 64 + ni * 16 + cc;
        const float bv = bias[gc];
#pragma unroll
        for (int mi = 0; mi < 4; mi++) {
            const int gr = bm + wm * 64 + mi * 16 + cr;
            float* cp = C + (size_t)gr * N + gc;
#pragma unroll
            for (int r = 0; r < 4; r++) cp[(size_t)r * N] = acc[mi][ni][r] + bv;
        }
    }
}

// ---------------- per-(b,h) LIF scan over a time chunk (chunk-local I/O) ----------------
__global__ __launch_bounds__(256)
void scan_kernel(const float* __restrict__ cur, float* __restrict__ dst,
                 float* __restrict__ mst, float* __restrict__ spst,
                 _Float16* __restrict__ sout, const float* __restrict__ tau_m,
                 const float* __restrict__ tau_n) {
    int idx = blockIdx.x * 256 + threadIdx.x;  // b*H + h
    int b = idx >> 9;
    int h = idx & (H_ - 1);

    float alpha = 1.f / (1.f + expf(-tau_m[h]));
    float4 tn = ((const float4*)tau_n)[h];
    float4 beta;
    beta.x = 1.f / (1.f + expf(-tn.x));
    beta.y = 1.f / (1.f + expf(-tn.y));
    beta.z = 1.f / (1.f + expf(-tn.z));
    beta.w = 1.f / (1.f + expf(-tn.w));

    float4 d = ((const float4*)dst)[idx];
    float m = mst[idx];
    float sp = spst[idx];

    const float* cp = cur + (size_t)b * TC_ * HB_ + h * BR_;
    _Float16* so = sout + (size_t)b * TC_ * H_ + h;

    for (int t = 0; t < TC_; t++) {
        float4 c = *(const float4*)cp;
        cp += HB_;
        d.x = beta.x * d.x + (1.f - beta.x) * c.x;
        d.y = beta.y * d.y + (1.f - beta.y) * c.y;
        d.z = beta.z * d.z + (1.f - beta.z) * c.z;
        d.w = beta.w * d.w + (1.f - beta.w) * c.w;
        float s4 = ((d.x + d.y) + d.z) + d.w;
        m = m * alpha + (1.f - alpha) * s4 - VTH_ * sp;
        sp = (m > VTH_) ? 1.f : 0.f;
        *so = (_Float16)sp;
        so += H_;
    }

    ((float4*)dst)[idx] = d;
    mst[idx] = m;
    spst[idx] = sp;
}

// ---------------- readout small GEMM: curo[b*T+t, o] = s2c[r,:] . Wo[o,:] + bo[o] ----------------
__global__ __launch_bounds__(256)
void rdot_kernel(const _Float16* __restrict__ s2c, const float* __restrict__ Wo,
                 const float* __restrict__ bo, float* __restrict__ curo, int t0) {
    int tid = blockIdx.x * 256 + threadIdx.x;   // MCH_*32 threads
    int r = tid >> 5;
    int n = tid & 31;
    if (n >= OUT_) return;
    const _Float16* a = s2c + (size_t)r * H_;
    const float*    w = Wo + (size_t)n * H_;
    float acc = bo[n];
    for (int k = 0; k < H_; k += 4) {
        acc += (float)a[k] * w[k] + (float)a[k + 1] * w[k + 1]
             + (float)a[k + 2] * w[k + 2] + (float)a[k + 3] * w[k + 3];
    }
    int bb = r / TC_, tl = r - bb * TC_;
    curo[((size_t)bb * T_ + t0 + tl) * OUT_ + n] = acc;
}

// ---------------- readout: leaky integrator + per-step softmax + sum ----------------
__global__ __launch_bounds__(64)
void readout_kernel(const float* __restrict__ curo, const float* __restrict__ tau_mo,
                    float* __restrict__ out) {
    int b = blockIdx.x;
    int o = threadIdx.x;
    bool act = (o < OUT_);
    float ao = 1.f / (1.f + expf(-tau_mo[act ? o : 0]));
    float mo = 0.f, accv = 0.f;
    const float* cp = curo + (size_t)b * T_ * OUT_;
    for (int t = 0; t < T_; t++) {
        float c = act ? cp[t * OUT_ + o] : 0.f;
        mo = mo * ao + (1.f - ao) * c;
        float v = act ? mo : -3.0e38f;
#pragma unroll
        for (int s = 16; s > 0; s >>= 1) v = fmaxf(v, __shfl_xor(v, s, 32));
        float e = act ? expf(mo - v) : 0.f;
        float se = e;
#pragma unroll
        for (int s = 16; s > 0; s >>= 1) se += __shfl_xor(se, s, 32);
        if (t >= WARM_ + 1) accv += e / se;
    }
    if (act) out[b * OUT_ + o] = accv;
}

extern "C" void kernel_launch(void* const* d_in, const int* in_sizes, int n_in,
                              void* d_out, int out_size, void* d_ws, size_t ws_size,
                              hipStream_t stream) {
    const float* x      = (const float*)d_in[0];
    const float* W1     = (const float*)d_in[1];
    const float* b1     = (const float*)d_in[2];
    const float* tau_m1 = (const float*)d_in[3];
    const float* tau_n1 = (const float*)d_in[4];
    const float* mask1  = (const float*)d_in[5];
    const float* W2     = (const float*)d_in[6];
    const float* b2     = (const float*)d_in[7];
    const float* tau_m2 = (const float*)d_in[8];
    const float* tau_n2 = (const float*)d_in[9];
    const float* mask2  = (const float*)d_in[10];
    const float* Wo     = (const float*)d_in[11];
    const float* bo     = (const float*)d_in[12];
    const float* tau_mo = (const float*)d_in[13];
    float* out = (float*)d_out;

    // workspace layout (byte allocator, 256B aligned)
    char* p = (char*)d_ws;
    auto alloc = [&](size_t bytes) { char* r = p; p += (bytes + 255) & ~(size_t)255; return r; };
    _Float16* w10 = (_Float16*)alloc((size_t)HB_ * INP_ * 2);
    _Float16* w11 = (_Float16*)alloc((size_t)HB_ * INP_ * 2);
    _Float16* w20 = (_Float16*)alloc((size_t)HB_ * H_ * 2);
    _Float16* w21 = (_Float16*)alloc((size_t)HB_ * H_ * 2);
    _Float16* w22 = (_Float16*)alloc((size_t)HB_ * H_ * 2);
    _Float16* xc0 = (_Float16*)alloc((size_t)MCH_ * INP_ * 2);
    _Float16* xc1 = (_Float16*)alloc((size_t)MCH_ * INP_ * 2);
    _Float16* s1c = (_Float16*)alloc((size_t)MCH_ * H_ * 2);
    _Float16* s2c = (_Float16*)alloc((size_t)MCH_ * H_ * 2);
    float* cur    = (float*)alloc((size_t)MCH_ * HB_ * 4);
    float* curo   = (float*)alloc((size_t)B_ * T_ * OUT_ * 4);
    float* st     = (float*)alloc((size_t)786432 * 4);  // d1,m1,sp1,d2,m2,sp2
    float* d1  = st;
    float* m1  = d1 + (size_t)B_ * H_ * BR_;
    float* sp1 = m1 + (size_t)B_ * H_;
    float* d2  = sp1 + (size_t)B_ * H_;
    float* m2  = d2 + (size_t)B_ * H_ * BR_;
    float* sp2 = m2 + (size_t)B_ * H_;

    // prep
    w1prep_kernel<<<(HB_ * INP_ + 255) / 256, 256, 0, stream>>>(W1, mask1, w10, w11);
    w2prep_kernel<<<(HB_ * H_ + 255) / 256, 256, 0, stream>>>(W2, mask2, w20, w21, w22);
    zero_kernel<<<(786432 / 4 + 255) / 256, 256, 0, stream>>>(st, 786432 / 4);

    Segs seg1; seg1.a[0] = xc0; seg1.a[1] = xc0; seg1.a[2] = xc1;
               seg1.w[0] = w10; seg1.w[1] = w11; seg1.w[2] = w10;
    Segs seg2; seg2.a[0] = s1c; seg2.a[1] = s1c; seg2.a[2] = s1c;
               seg2.w[0] = w20; seg2.w[1] = w21; seg2.w[2] = w22;

    dim3 gg(HB_ / 128, MCH_ / 128);   // (16, 50)
    const int NCH = T_ / TC_;
    for (int c = 0; c < NCH; c++) {
        int t0 = c * TC_;
        convx_kernel<<<(MCH_ * INP_) / 256, 256, 0, stream>>>(x, xc0, xc1, t0);
        mfma_gemm_kernel<<<gg, 256, 0, stream>>>(seg1, INP_ / 32, INP_, b1, cur, HB_);
        scan_kernel<<<B_ * H_ / 256, 256, 0, stream>>>(cur, d1, m1, sp1, s1c, tau_m1, tau_n1);
        mfma_gemm_kernel<<<gg, 256, 0, stream>>>(seg2, H_ / 32, H_, b2, cur, HB_);
        scan_kernel<<<B_ * H_ / 256, 256, 0, stream>>>(cur, d2, m2, sp2, s2c, tau_m2, tau_n2);
        rdot_kernel<<<MCH_ * 32 / 256, 256, 0, stream>>>(s2c, Wo, bo, curo, t0);
    }
    readout_kernel<<<B_, 64, 0, stream>>>(curo, tau_mo, out);
}

// Round 3
// 1283.385 us; speedup vs baseline: 1.9159x; 1.2224x over previous
//
#include <hip/hip_runtime.h>
#include <math.h>
#include <stdint.h>

// Problem dims
#define B_    128
#define T_    250
#define IN_   700
#define INP_  704    // padded to 32
#define H_    512
#define OUT_  20
#define BR_   4
#define HB_   2048   // H_*BR_
#define TC_   50     // time chunk
#define MCH_  6400   // B_*TC_ rows per chunk
#define WARM_ 10
#define VTH_  1.0f

typedef __attribute__((ext_vector_type(8))) _Float16 half8;
typedef __attribute__((ext_vector_type(4))) float f32x4;
typedef __attribute__((ext_vector_type(4))) int i32x4;
typedef const __attribute__((address_space(1))) void* gptr_t;
typedef __attribute__((address_space(3))) void* lptr_t;

struct Segs { const _Float16* a[3]; const _Float16* w[3]; };

// ---------------- prep: split fp32 -> hi/lo fp16 planes (layer 1) ----------------
__global__ __launch_bounds__(256)
void w1prep_kernel(const float* __restrict__ W, const float* __restrict__ M,
                   _Float16* __restrict__ w0, _Float16* __restrict__ w1) {
    int i = blockIdx.x * 256 + threadIdx.x;           // over HB_*INP_
    if (i >= HB_ * INP_) return;
    int r = i / INP_, c = i - r * INP_;
    float v = (c < IN_) ? W[(size_t)r * IN_ + c] * M[(size_t)r * IN_ + c] : 0.f;
    _Float16 h0 = (_Float16)v;
    w0[i] = h0;
    w1[i] = (_Float16)(v - (float)h0);
}

// ---------------- prep: layer-2 weights -> 3 signed radix-256 i8 planes, scale 2^26 ----------------
__global__ __launch_bounds__(256)
void w2prep_kernel(const float* __restrict__ W, const float* __restrict__ M,
                   int8_t* __restrict__ p2, int8_t* __restrict__ p1,
                   int8_t* __restrict__ p0) {
    int i = blockIdx.x * 256 + threadIdx.x;           // over HB_*H_
    if (i >= HB_ * H_) return;
    float v = W[i] * M[i];
    int q = (int)lrintf(v * 67108864.f);              // |q| <= 0.0442*2^26 ~ 2.97e6
    int b0 = (int)(int8_t)(q & 0xFF);  q = (q - b0) >> 8;
    int b1 = (int)(int8_t)(q & 0xFF);  int b2 = (q - b1) >> 8;   // |b2| <= 46
    p0[i] = (int8_t)b0; p1[i] = (int8_t)b1; p2[i] = (int8_t)b2;
}

// per-chunk x conversion: global rows (bb*T_+t0+tl) -> chunk-local [MCH_, INP_]
__global__ __launch_bounds__(256)
void convx_kernel(const float* __restrict__ x, _Float16* __restrict__ x0,
                  _Float16* __restrict__ x1, int t0) {
    int i = blockIdx.x * 256 + threadIdx.x;           // over MCH_*INP_
    if (i >= MCH_ * INP_) return;
    int r = i / INP_, c = i - r * INP_;
    int bb = r / TC_, tl = r - bb * TC_;
    float v = (c < IN_) ? x[((size_t)bb * T_ + t0 + tl) * IN_ + c] : 0.f;
    _Float16 h0 = (_Float16)v;
    x0[i] = h0;
    x1[i] = (_Float16)(v - (float)h0);
}

__global__ void zero_kernel(float* __restrict__ p, int n4) {
    int i = blockIdx.x * blockDim.x + threadIdx.x;
    if (i < n4) ((float4*)p)[i] = make_float4(0.f, 0.f, 0.f, 0.f);
}

// ---------------- segmented-K fp16 MFMA GEMM (layer 1) ----------------
__global__ __launch_bounds__(256)
void mfma_gemm_kernel(Segs segs, int ktiles, int ld,
                      const float* __restrict__ bias, float* __restrict__ C, int N) {
    __shared__ alignas(16) _Float16 As[128 * 32];
    __shared__ alignas(16) _Float16 Bs[128 * 32];
    const int tid  = threadIdx.x;
    const int wave = tid >> 6, lane = tid & 63;
    const int bm = blockIdx.y * 128, bn = blockIdx.x * 128;

    const int    srow  = tid >> 2;
    const int    skoff = (tid & 3) * 8;
    const size_t aoff0 = (size_t)(bm + srow) * ld + skoff;
    const size_t aoff1 = aoff0 + (size_t)64 * ld;
    const size_t boff0 = (size_t)(bn + srow) * ld + skoff;
    const size_t boff1 = boff0 + (size_t)64 * ld;
    lptr_t lA0 = (lptr_t)(As + wave * 512);
    lptr_t lA1 = (lptr_t)(As + 2048 + wave * 512);
    lptr_t lB0 = (lptr_t)(Bs + wave * 512);
    lptr_t lB1 = (lptr_t)(Bs + 2048 + wave * 512);

    const int wm = wave & 1, wn = wave >> 1;
    const int fr = lane & 15;
    const int fk = (lane >> 4) * 8;

    f32x4 acc[4][4] = {};

#pragma unroll
    for (int s = 0; s < 3; s++) {
        const _Float16* pa = segs.a[s];
        const _Float16* pw = segs.w[s];
        for (int kt = 0; kt < ktiles; kt++) {
            const int k0 = kt * 32;
            __builtin_amdgcn_global_load_lds((gptr_t)(pa + aoff0 + k0), lA0, 16, 0, 0);
            __builtin_amdgcn_global_load_lds((gptr_t)(pa + aoff1 + k0), lA1, 16, 0, 0);
            __builtin_amdgcn_global_load_lds((gptr_t)(pw + boff0 + k0), lB0, 16, 0, 0);
            __builtin_amdgcn_global_load_lds((gptr_t)(pw + boff1 + k0), lB1, 16, 0, 0);
            __syncthreads();

            half8 af[4], bf[4];
#pragma unroll
            for (int mi = 0; mi < 4; mi++)
                af[mi] = *(const half8*)&As[(wm * 64 + mi * 16 + fr) * 32 + fk];
#pragma unroll
            for (int ni = 0; ni < 4; ni++)
                bf[ni] = *(const half8*)&Bs[(wn * 64 + ni * 16 + fr) * 32 + fk];
#pragma unroll
            for (int mi = 0; mi < 4; mi++)
#pragma unroll
                for (int ni = 0; ni < 4; ni++)
                    acc[mi][ni] = __builtin_amdgcn_mfma_f32_16x16x32_f16(
                        af[mi], bf[ni], acc[mi][ni], 0, 0, 0);
            __syncthreads();
        }
    }

    const int cc = lane & 15;
    const int cr = (lane >> 4) * 4;
#pragma unroll
    for (int ni = 0; ni < 4; ni++) {
        const int gc = bn + wn * 64 + ni * 16 + cc;
        const float bv = bias[gc];
#pragma unroll
        for (int mi = 0; mi < 4; mi++) {
            const int gr = bm + wm * 64 + mi * 16 + cr;
            float* cp = C + (size_t)gr * N + gc;
#pragma unroll
            for (int r = 0; r < 4; r++) cp[(size_t)r * N] = acc[mi][ni][r] + bv;
        }
    }
}

// ---------------- i8 fixed-point MFMA GEMM (layer 2): exact Horner over 3 planes ----------------
// C[m,n] = (sum_k s[m,k] * q[n,k]) / 2^26 + bias[n];  A: i8 spikes [MCH_][512]
__global__ __launch_bounds__(256)
void mfma_i8_gemm_kernel(const int8_t* __restrict__ A,
                         const int8_t* __restrict__ p2, const int8_t* __restrict__ p1,
                         const int8_t* __restrict__ p0,
                         const float* __restrict__ bias, float* __restrict__ C) {
    __shared__ alignas(16) int8_t As[128 * 64];   // 8 KB, K-tile 64
    __shared__ alignas(16) int8_t Bs[128 * 64];
    const int tid  = threadIdx.x;
    const int wave = tid >> 6, lane = tid & 63;
    const int bm = blockIdx.y * 128, bn = blockIdx.x * 128;

    const int    srow  = tid >> 2;
    const int    skoff = (tid & 3) * 16;
    const size_t aoff0 = (size_t)(bm + srow) * H_ + skoff;
    const size_t aoff1 = aoff0 + (size_t)64 * H_;
    const size_t boff0 = (size_t)(bn + srow) * H_ + skoff;
    const size_t boff1 = boff0 + (size_t)64 * H_;
    lptr_t lA0 = (lptr_t)(As + wave * 1024);
    lptr_t lA1 = (lptr_t)(As + 4096 + wave * 1024);
    lptr_t lB0 = (lptr_t)(Bs + wave * 1024);
    lptr_t lB1 = (lptr_t)(Bs + 4096 + wave * 1024);

    const int wm = wave & 1, wn = wave >> 1;
    const int fr = lane & 15;
    const int fk = (lane >> 4) * 16;   // byte (=element) offset within 64-K tile

    const int8_t* planes[3] = {p2, p1, p0};
    i32x4 acc[4][4] = {};

#pragma unroll
    for (int s = 0; s < 3; s++) {
        if (s) {
#pragma unroll
            for (int mi = 0; mi < 4; mi++)
#pragma unroll
                for (int ni = 0; ni < 4; ni++) acc[mi][ni] *= 256;  // exact, |acc|<1.6e9
        }
        const int8_t* pw = planes[s];
        for (int kt = 0; kt < H_ / 64; kt++) {
            const int k0 = kt * 64;
            __builtin_amdgcn_global_load_lds((gptr_t)(A  + aoff0 + k0), lA0, 16, 0, 0);
            __builtin_amdgcn_global_load_lds((gptr_t)(A  + aoff1 + k0), lA1, 16, 0, 0);
            __builtin_amdgcn_global_load_lds((gptr_t)(pw + boff0 + k0), lB0, 16, 0, 0);
            __builtin_amdgcn_global_load_lds((gptr_t)(pw + boff1 + k0), lB1, 16, 0, 0);
            __syncthreads();

            i32x4 af[4], bf[4];
#pragma unroll
            for (int mi = 0; mi < 4; mi++)
                af[mi] = *(const i32x4*)&As[(wm * 64 + mi * 16 + fr) * 64 + fk];
#pragma unroll
            for (int ni = 0; ni < 4; ni++)
                bf[ni] = *(const i32x4*)&Bs[(wn * 64 + ni * 16 + fr) * 64 + fk];
#pragma unroll
            for (int mi = 0; mi < 4; mi++)
#pragma unroll
                for (int ni = 0; ni < 4; ni++)
                    acc[mi][ni] = __builtin_amdgcn_mfma_i32_16x16x64_i8(
                        af[mi], bf[ni], acc[mi][ni], 0, 0, 0);
            __syncthreads();
        }
    }

    const float scale = 1.f / 67108864.f;
    const int cc = lane & 15;
    const int cr = (lane >> 4) * 4;
#pragma unroll
    for (int ni = 0; ni < 4; ni++) {
        const int gc = bn + wn * 64 + ni * 16 + cc;
        const float bv = bias[gc];
#pragma unroll
        for (int mi = 0; mi < 4; mi++) {
            const int gr = bm + wm * 64 + mi * 16 + cr;
            float* cp = C + (size_t)gr * HB_ + gc;
#pragma unroll
            for (int r = 0; r < 4; r++)
                cp[(size_t)r * HB_] = (float)acc[mi][ni][r] * scale + bv;
        }
    }
}

// ---------------- per-(b,h) LIF scans (i8 spike out for L1, fp16 out for L2) ----------------
#define SCAN_BODY(SPIKE_STORE)                                                  \
    int idx = blockIdx.x * 256 + threadIdx.x;                                   \
    int b = idx >> 9;                                                           \
    int h = idx & (H_ - 1);                                                     \
    float alpha = 1.f / (1.f + expf(-tau_m[h]));                                \
    float4 tn = ((const float4*)tau_n)[h];                                      \
    float4 beta;                                                                \
    beta.x = 1.f / (1.f + expf(-tn.x));                                         \
    beta.y = 1.f / (1.f + expf(-tn.y));                                         \
    beta.z = 1.f / (1.f + expf(-tn.z));                                         \
    beta.w = 1.f / (1.f + expf(-tn.w));                                         \
    float4 d = ((const float4*)dst)[idx];                                       \
    float m = mst[idx];                                                         \
    float sp = spst[idx];                                                       \
    const float* cp = cur + (size_t)b * TC_ * HB_ + h * BR_;                    \
    for (int t = 0; t < TC_; t++) {                                             \
        float4 c = *(const float4*)cp;                                          \
        cp += HB_;                                                              \
        d.x = beta.x * d.x + (1.f - beta.x) * c.x;                              \
        d.y = beta.y * d.y + (1.f - beta.y) * c.y;                              \
        d.z = beta.z * d.z + (1.f - beta.z) * c.z;                              \
        d.w = beta.w * d.w + (1.f - beta.w) * c.w;                              \
        float s4 = ((d.x + d.y) + d.z) + d.w;                                   \
        m = m * alpha + (1.f - alpha) * s4 - VTH_ * sp;                         \
        sp = (m > VTH_) ? 1.f : 0.f;                                            \
        SPIKE_STORE;                                                            \
    }                                                                           \
    ((float4*)dst)[idx] = d;                                                    \
    mst[idx] = m;                                                               \
    spst[idx] = sp;

__global__ __launch_bounds__(256)
void scan_i8_kernel(const float* __restrict__ cur, float* __restrict__ dst,
                    float* __restrict__ mst, float* __restrict__ spst,
                    int8_t* __restrict__ sout, const float* __restrict__ tau_m,
                    const float* __restrict__ tau_n) {
    int8_t* so_base = sout;
    SCAN_BODY(so_base[((size_t)b * TC_ + t) * H_ + h] = (int8_t)(m > VTH_))
}

__global__ __launch_bounds__(256)
void scan_f16_kernel(const float* __restrict__ cur, float* __restrict__ dst,
                     float* __restrict__ mst, float* __restrict__ spst,
                     _Float16* __restrict__ sout, const float* __restrict__ tau_m,
                     const float* __restrict__ tau_n) {
    _Float16* so_base = sout;
    SCAN_BODY(so_base[((size_t)b * TC_ + t) * H_ + h] = (_Float16)sp)
}

// ---------------- readout small GEMM: curo[b,t,o] = s2c[r,:] . Wo[o,:] + bo[o] ----------------
__global__ __launch_bounds__(256)
void rdot_kernel(const _Float16* __restrict__ s2c, const float* __restrict__ Wo,
                 const float* __restrict__ bo, float* __restrict__ curo, int t0) {
    int tid = blockIdx.x * 256 + threadIdx.x;   // MCH_*32 threads
    int r = tid >> 5;
    int n = tid & 31;
    if (n >= OUT_) return;
    const _Float16* a = s2c + (size_t)r * H_;
    const float*    w = Wo + (size_t)n * H_;
    float acc = bo[n];
    for (int k = 0; k < H_; k += 4) {
        acc += (float)a[k] * w[k] + (float)a[k + 1] * w[k + 1]
             + (float)a[k + 2] * w[k + 2] + (float)a[k + 3] * w[k + 3];
    }
    int bb = r / TC_, tl = r - bb * TC_;
    curo[((size_t)bb * T_ + t0 + tl) * OUT_ + n] = acc;
}

// ---------------- parallel readout: segmented scan + t-parallel softmax-sum ----------------
#define RT_SEG 12
#define RT_LEN 21   // 12*21 = 252 >= 250

__global__ __launch_bounds__(256)
void readout_kernel(const float* __restrict__ curo, const float* __restrict__ tau_mo,
                    float* __restrict__ out) {
    __shared__ float moS[T_ * OUT_];          // 20 KB
    __shared__ float segA[RT_SEG][OUT_];
    __shared__ float segU[RT_SEG][OUT_];
    __shared__ float pre[RT_SEG][OUT_];
    __shared__ float accS[OUT_];
    const int b = blockIdx.x;
    const int tid = threadIdx.x;
    const float* cb = curo + (size_t)b * T_ * OUT_;

    const int o = tid % OUT_;
    const int sg = tid / OUT_;
    const float ao = 1.f / (1.f + expf(-tau_mo[o]));

    if (tid < RT_SEG * OUT_) {
        int t0 = sg * RT_LEN;
        int t1 = min(T_, t0 + RT_LEN);
        float u = 0.f, Ap = 1.f;
        for (int t = t0; t < t1; t++) {
            u = ao * u + (1.f - ao) * cb[t * OUT_ + o];
            Ap *= ao;
        }
        segU[sg][o] = u; segA[sg][o] = Ap;
    }
    if (tid < OUT_) accS[tid] = 0.f;
    __syncthreads();
    if (tid < OUT_) {
        float m = 0.f;
        for (int s = 0; s < RT_SEG; s++) {
            pre[s][tid] = m;
            m = segA[s][tid] * m + segU[s][tid];
        }
    }
    __syncthreads();
    if (tid < RT_SEG * OUT_) {
        int t0 = sg * RT_LEN;
        int t1 = min(T_, t0 + RT_LEN);
        float m = pre[sg][o];
        for (int t = t0; t < t1; t++) {
            m = ao * m + (1.f - ao) * cb[t * OUT_ + o];
            moS[t * OUT_ + o] = m;
        }
    }
    __syncthreads();
    if (tid >= WARM_ + 1 && tid < T_) {
        int t = tid;
        float mx = -3.0e38f;
#pragma unroll
        for (int o2 = 0; o2 < OUT_; o2++) mx = fmaxf(mx, moS[t * OUT_ + o2]);
        float es[OUT_]; float se = 0.f;
#pragma unroll
        for (int o2 = 0; o2 < OUT_; o2++) {
            float e = expf(moS[t * OUT_ + o2] - mx);
            es[o2] = e; se += e;
        }
        float inv = 1.f / se;
#pragma unroll
        for (int o2 = 0; o2 < OUT_; o2++) atomicAdd(&accS[o2], es[o2] * inv);
    }
    __syncthreads();
    if (tid < OUT_) out[(size_t)b * OUT_ + tid] = accS[tid];
}

extern "C" void kernel_launch(void* const* d_in, const int* in_sizes, int n_in,
                              void* d_out, int out_size, void* d_ws, size_t ws_size,
                              hipStream_t stream) {
    const float* x      = (const float*)d_in[0];
    const float* W1     = (const float*)d_in[1];
    const float* b1     = (const float*)d_in[2];
    const float* tau_m1 = (const float*)d_in[3];
    const float* tau_n1 = (const float*)d_in[4];
    const float* mask1  = (const float*)d_in[5];
    const float* W2     = (const float*)d_in[6];
    const float* b2     = (const float*)d_in[7];
    const float* tau_m2 = (const float*)d_in[8];
    const float* tau_n2 = (const float*)d_in[9];
    const float* mask2  = (const float*)d_in[10];
    const float* Wo     = (const float*)d_in[11];
    const float* bo     = (const float*)d_in[12];
    const float* tau_mo = (const float*)d_in[13];
    float* out = (float*)d_out;

    char* p = (char*)d_ws;
    auto alloc = [&](size_t bytes) { char* r = p; p += (bytes + 255) & ~(size_t)255; return r; };
    _Float16* w10 = (_Float16*)alloc((size_t)HB_ * INP_ * 2);
    _Float16* w11 = (_Float16*)alloc((size_t)HB_ * INP_ * 2);
    int8_t*   q2  = (int8_t*)alloc((size_t)HB_ * H_);
    int8_t*   q1  = (int8_t*)alloc((size_t)HB_ * H_);
    int8_t*   q0  = (int8_t*)alloc((size_t)HB_ * H_);
    _Float16* xc0 = (_Float16*)alloc((size_t)MCH_ * INP_ * 2);
    _Float16* xc1 = (_Float16*)alloc((size_t)MCH_ * INP_ * 2);
    int8_t*   s1c = (int8_t*)alloc((size_t)MCH_ * H_);
    _Float16* s2c = (_Float16*)alloc((size_t)MCH_ * H_ * 2);
    float* cur    = (float*)alloc((size_t)MCH_ * HB_ * 4);
    float* curo   = (float*)alloc((size_t)B_ * T_ * OUT_ * 4);
    float* st     = (float*)alloc((size_t)786432 * 4);
    float* d1  = st;
    float* m1  = d1 + (size_t)B_ * H_ * BR_;
    float* sp1 = m1 + (size_t)B_ * H_;
    float* d2  = sp1 + (size_t)B_ * H_;
    float* m2  = d2 + (size_t)B_ * H_ * BR_;
    float* sp2 = m2 + (size_t)B_ * H_;

    w1prep_kernel<<<(HB_ * INP_ + 255) / 256, 256, 0, stream>>>(W1, mask1, w10, w11);
    w2prep_kernel<<<(HB_ * H_ + 255) / 256, 256, 0, stream>>>(W2, mask2, q2, q1, q0);
    zero_kernel<<<(786432 / 4 + 255) / 256, 256, 0, stream>>>(st, 786432 / 4);

    Segs seg1; seg1.a[0] = xc0; seg1.a[1] = xc0; seg1.a[2] = xc1;
               seg1.w[0] = w10; seg1.w[1] = w11; seg1.w[2] = w10;

    dim3 gg(HB_ / 128, MCH_ / 128);   // (16, 50)
    const int NCH = T_ / TC_;
    for (int c = 0; c < NCH; c++) {
        int t0 = c * TC_;
        convx_kernel<<<(MCH_ * INP_) / 256, 256, 0, stream>>>(x, xc0, xc1, t0);
        mfma_gemm_kernel<<<gg, 256, 0, stream>>>(seg1, INP_ / 32, INP_, b1, cur, HB_);
        scan_i8_kernel<<<B_ * H_ / 256, 256, 0, stream>>>(cur, d1, m1, sp1, s1c, tau_m1, tau_n1);
        mfma_i8_gemm_kernel<<<gg, 256, 0, stream>>>(s1c, q2, q1, q0, b2, cur);
        scan_f16_kernel<<<B_ * H_ / 256, 256, 0, stream>>>(cur, d2, m2, sp2, s2c, tau_m2, tau_n2);
        rdot_kernel<<<MCH_ * 32 / 256, 256, 0, stream>>>(s2c, Wo, bo, curo, t0);
    }
    readout_kernel<<<B_, 256, 0, stream>>>(curo, tau_mo, out);
}

// Round 4
// 1115.180 us; speedup vs baseline: 2.2049x; 1.1508x over previous
//
#include <hip/hip_runtime.h>
#include <math.h>
#include <stdint.h>

// Problem dims
#define B_    128
#define T_    250
#define IN_   700
#define INP_  704    // padded to 32
#define H_    512
#define OUT_  20
#define BR_   4
#define HB_   2048   // H_*BR_
#define TCMAX 100    // max time chunk
#define WARM_ 10
#define VTH_  1.0f

typedef __attribute__((ext_vector_type(8))) _Float16 half8;
typedef __attribute__((ext_vector_type(4))) float f32x4;
typedef __attribute__((ext_vector_type(4))) int i32x4;
typedef const __attribute__((address_space(1))) void* gptr_t;
typedef __attribute__((address_space(3))) void* lptr_t;

// ---------------- prep: split fp32 -> hi/lo fp16 planes (layer 1) ----------------
__global__ __launch_bounds__(256)
void w1prep_kernel(const float* __restrict__ W, const float* __restrict__ M,
                   _Float16* __restrict__ w0, _Float16* __restrict__ w1) {
    int i = blockIdx.x * 256 + threadIdx.x;           // over HB_*INP_
    if (i >= HB_ * INP_) return;
    int r = i / INP_, c = i - r * INP_;
    float v = (c < IN_) ? W[(size_t)r * IN_ + c] * M[(size_t)r * IN_ + c] : 0.f;
    _Float16 h0 = (_Float16)v;
    w0[i] = h0;
    w1[i] = (_Float16)(v - (float)h0);
}

// ---------------- prep: layer-2 weights -> 3 signed radix-256 i8 planes, scale 2^26 ----------------
__global__ __launch_bounds__(256)
void w2prep_kernel(const float* __restrict__ W, const float* __restrict__ M,
                   int8_t* __restrict__ p2, int8_t* __restrict__ p1,
                   int8_t* __restrict__ p0) {
    int i = blockIdx.x * 256 + threadIdx.x;           // over HB_*H_
    if (i >= HB_ * H_) return;
    float v = W[i] * M[i];
    int q = (int)lrintf(v * 67108864.f);              // |q| <= 0.0442*2^26 ~ 2.97e6
    int b0 = (int)(int8_t)(q & 0xFF);  q = (q - b0) >> 8;
    int b1 = (int)(int8_t)(q & 0xFF);  int b2 = (q - b1) >> 8;   // |b2| <= 46
    p0[i] = (int8_t)b0; p1[i] = (int8_t)b1; p2[i] = (int8_t)b2;
}

// per-chunk x conversion: global rows (bb*T_+t0+tl) -> chunk-local [128*tc, INP_]
__global__ __launch_bounds__(256)
void convx_kernel(const float* __restrict__ x, _Float16* __restrict__ x0,
                  _Float16* __restrict__ x1, int t0, int tc, int ntot) {
    int i = blockIdx.x * 256 + threadIdx.x;
    if (i >= ntot) return;
    int r = i / INP_, c = i - r * INP_;
    int bb = r / tc, tl = r - bb * tc;
    float v = (c < IN_) ? x[((size_t)bb * T_ + t0 + tl) * IN_ + c] : 0.f;
    _Float16 h0 = (_Float16)v;
    x0[i] = h0;
    x1[i] = (_Float16)(v - (float)h0);
}

__global__ void zero_kernel(float* __restrict__ p, int n4) {
    int i = blockIdx.x * blockDim.x + threadIdx.x;
    if (i < n4) ((float4*)p)[i] = make_float4(0.f, 0.f, 0.f, 0.f);
}

// ---------------- L1 GEMM: k-major, 3 products (x0w0 + x0w1 + x1w0) in one acc ----------------
// C[m,n] = x[m,:].w[n,:] + bias[n]; A chunk-local [M][INP_], W [HB_][INP_]
__global__ __launch_bounds__(256)
void l1_gemm_kernel(const _Float16* __restrict__ x0, const _Float16* __restrict__ x1,
                    const _Float16* __restrict__ w0, const _Float16* __restrict__ w1,
                    const float* __restrict__ bias, float* __restrict__ C) {
    __shared__ alignas(16) _Float16 A0s[128 * 32];
    __shared__ alignas(16) _Float16 A1s[128 * 32];
    __shared__ alignas(16) _Float16 B0s[128 * 32];
    __shared__ alignas(16) _Float16 B1s[128 * 32];
    const int tid  = threadIdx.x;
    const int wave = tid >> 6, lane = tid & 63;
    const int bm = blockIdx.y * 128, bn = blockIdx.x * 128;

    const int    srow  = tid >> 2;
    const int    skoff = (tid & 3) * 8;
    const size_t aoff0 = (size_t)(bm + srow) * INP_ + skoff;
    const size_t aoff1 = aoff0 + (size_t)64 * INP_;
    const size_t boff0 = (size_t)(bn + srow) * INP_ + skoff;
    const size_t boff1 = boff0 + (size_t)64 * INP_;
    const int lo0 = wave * 512, lo1 = 2048 + wave * 512;

    const int wm = wave & 1, wn = wave >> 1;
    const int fr = lane & 15;
    const int fk = (lane >> 4) * 8;

    f32x4 acc[4][4] = {};

    for (int kt = 0; kt < INP_ / 32; kt++) {
        const int k0 = kt * 32;
        __builtin_amdgcn_global_load_lds((gptr_t)(x0 + aoff0 + k0), (lptr_t)(A0s + lo0), 16, 0, 0);
        __builtin_amdgcn_global_load_lds((gptr_t)(x0 + aoff1 + k0), (lptr_t)(A0s + lo1), 16, 0, 0);
        __builtin_amdgcn_global_load_lds((gptr_t)(x1 + aoff0 + k0), (lptr_t)(A1s + lo0), 16, 0, 0);
        __builtin_amdgcn_global_load_lds((gptr_t)(x1 + aoff1 + k0), (lptr_t)(A1s + lo1), 16, 0, 0);
        __builtin_amdgcn_global_load_lds((gptr_t)(w0 + boff0 + k0), (lptr_t)(B0s + lo0), 16, 0, 0);
        __builtin_amdgcn_global_load_lds((gptr_t)(w0 + boff1 + k0), (lptr_t)(B0s + lo1), 16, 0, 0);
        __builtin_amdgcn_global_load_lds((gptr_t)(w1 + boff0 + k0), (lptr_t)(B1s + lo0), 16, 0, 0);
        __builtin_amdgcn_global_load_lds((gptr_t)(w1 + boff1 + k0), (lptr_t)(B1s + lo1), 16, 0, 0);
        __syncthreads();

        half8 a0[4], a1[4], b0[4], b1[4];
#pragma unroll
        for (int mi = 0; mi < 4; mi++)
            a0[mi] = *(const half8*)&A0s[(wm * 64 + mi * 16 + fr) * 32 + fk];
#pragma unroll
        for (int ni = 0; ni < 4; ni++)
            b0[ni] = *(const half8*)&B0s[(wn * 64 + ni * 16 + fr) * 32 + fk];
#pragma unroll
        for (int mi = 0; mi < 4; mi++)
#pragma unroll
            for (int ni = 0; ni < 4; ni++)
                acc[mi][ni] = __builtin_amdgcn_mfma_f32_16x16x32_f16(a0[mi], b0[ni], acc[mi][ni], 0, 0, 0);
#pragma unroll
        for (int ni = 0; ni < 4; ni++)
            b1[ni] = *(const half8*)&B1s[(wn * 64 + ni * 16 + fr) * 32 + fk];
#pragma unroll
        for (int mi = 0; mi < 4; mi++)
#pragma unroll
            for (int ni = 0; ni < 4; ni++)
                acc[mi][ni] = __builtin_amdgcn_mfma_f32_16x16x32_f16(a0[mi], b1[ni], acc[mi][ni], 0, 0, 0);
#pragma unroll
        for (int mi = 0; mi < 4; mi++)
            a1[mi] = *(const half8*)&A1s[(wm * 64 + mi * 16 + fr) * 32 + fk];
#pragma unroll
        for (int mi = 0; mi < 4; mi++)
#pragma unroll
            for (int ni = 0; ni < 4; ni++)
                acc[mi][ni] = __builtin_amdgcn_mfma_f32_16x16x32_f16(a1[mi], b0[ni], acc[mi][ni], 0, 0, 0);
        __syncthreads();
    }

    const int cc = lane & 15;
    const int cr = (lane >> 4) * 4;
#pragma unroll
    for (int ni = 0; ni < 4; ni++) {
        const int gc = bn + wn * 64 + ni * 16 + cc;
        const float bv = bias[gc];
#pragma unroll
        for (int mi = 0; mi < 4; mi++) {
            const int gr = bm + wm * 64 + mi * 16 + cr;
            float* cp = C + (size_t)gr * HB_ + gc;
#pragma unroll
            for (int r = 0; r < 4; r++) cp[(size_t)r * HB_] = acc[mi][ni][r] + bv;
        }
    }
}

// ---------------- i8 fixed-point MFMA GEMM (layer 2): exact Horner over 3 planes ----------------
__global__ __launch_bounds__(256)
void mfma_i8_gemm_kernel(const int8_t* __restrict__ A,
                         const int8_t* __restrict__ p2, const int8_t* __restrict__ p1,
                         const int8_t* __restrict__ p0,
                         const float* __restrict__ bias, float* __restrict__ C) {
    __shared__ alignas(16) int8_t As[128 * 64];   // 8 KB, K-tile 64
    __shared__ alignas(16) int8_t Bs[128 * 64];
    const int tid  = threadIdx.x;
    const int wave = tid >> 6, lane = tid & 63;
    const int bm = blockIdx.y * 128, bn = blockIdx.x * 128;

    const int    srow  = tid >> 2;
    const int    skoff = (tid & 3) * 16;
    const size_t aoff0 = (size_t)(bm + srow) * H_ + skoff;
    const size_t aoff1 = aoff0 + (size_t)64 * H_;
    const size_t boff0 = (size_t)(bn + srow) * H_ + skoff;
    const size_t boff1 = boff0 + (size_t)64 * H_;
    lptr_t lA0 = (lptr_t)(As + wave * 1024);
    lptr_t lA1 = (lptr_t)(As + 4096 + wave * 1024);
    lptr_t lB0 = (lptr_t)(Bs + wave * 1024);
    lptr_t lB1 = (lptr_t)(Bs + 4096 + wave * 1024);

    const int wm = wave & 1, wn = wave >> 1;
    const int fr = lane & 15;
    const int fk = (lane >> 4) * 16;

    const int8_t* planes[3] = {p2, p1, p0};
    i32x4 acc[4][4] = {};

#pragma unroll
    for (int s = 0; s < 3; s++) {
        if (s) {
#pragma unroll
            for (int mi = 0; mi < 4; mi++)
#pragma unroll
                for (int ni = 0; ni < 4; ni++) acc[mi][ni] *= 256;  // exact, |acc|<1.6e9
        }
        const int8_t* pw = planes[s];
        for (int kt = 0; kt < H_ / 64; kt++) {
            const int k0 = kt * 64;
            __builtin_amdgcn_global_load_lds((gptr_t)(A  + aoff0 + k0), lA0, 16, 0, 0);
            __builtin_amdgcn_global_load_lds((gptr_t)(A  + aoff1 + k0), lA1, 16, 0, 0);
            __builtin_amdgcn_global_load_lds((gptr_t)(pw + boff0 + k0), lB0, 16, 0, 0);
            __builtin_amdgcn_global_load_lds((gptr_t)(pw + boff1 + k0), lB1, 16, 0, 0);
            __syncthreads();

            i32x4 af[4], bf[4];
#pragma unroll
            for (int mi = 0; mi < 4; mi++)
                af[mi] = *(const i32x4*)&As[(wm * 64 + mi * 16 + fr) * 64 + fk];
#pragma unroll
            for (int ni = 0; ni < 4; ni++)
                bf[ni] = *(const i32x4*)&Bs[(wn * 64 + ni * 16 + fr) * 64 + fk];
#pragma unroll
            for (int mi = 0; mi < 4; mi++)
#pragma unroll
                for (int ni = 0; ni < 4; ni++)
                    acc[mi][ni] = __builtin_amdgcn_mfma_i32_16x16x64_i8(
                        af[mi], bf[ni], acc[mi][ni], 0, 0, 0);
            __syncthreads();
        }
    }

    const float scale = 1.f / 67108864.f;
    const int cc = lane & 15;
    const int cr = (lane >> 4) * 4;
#pragma unroll
    for (int ni = 0; ni < 4; ni++) {
        const int gc = bn + wn * 64 + ni * 16 + cc;
        const float bv = bias[gc];
#pragma unroll
        for (int mi = 0; mi < 4; mi++) {
            const int gr = bm + wm * 64 + mi * 16 + cr;
            float* cp = C + (size_t)gr * HB_ + gc;
#pragma unroll
            for (int r = 0; r < 4; r++)
                cp[(size_t)r * HB_] = (float)acc[mi][ni][r] * scale + bv;
        }
    }
}

// ---------------- per-(b,h) LIF scans over a time chunk (chunk-local I/O) ----------------
#define SCAN_BODY(SPIKE_STORE)                                                  \
    int idx = blockIdx.x * 256 + threadIdx.x;                                   \
    int b = idx >> 9;                                                           \
    int h = idx & (H_ - 1);                                                     \
    float alpha = 1.f / (1.f + expf(-tau_m[h]));                                \
    float4 tn = ((const float4*)tau_n)[h];                                      \
    float4 beta;                                                                \
    beta.x = 1.f / (1.f + expf(-tn.x));                                         \
    beta.y = 1.f / (1.f + expf(-tn.y));                                         \
    beta.z = 1.f / (1.f + expf(-tn.z));                                         \
    beta.w = 1.f / (1.f + expf(-tn.w));                                         \
    float4 d = ((const float4*)dst)[idx];                                       \
    float m = mst[idx];                                                         \
    float sp = spst[idx];                                                       \
    const float* cp = cur + (size_t)b * tc * HB_ + h * BR_;                     \
    for (int t = 0; t < tc; t++) {                                              \
        float4 c = *(const float4*)cp;                                          \
        cp += HB_;                                                              \
        d.x = beta.x * d.x + (1.f - beta.x) * c.x;                              \
        d.y = beta.y * d.y + (1.f - beta.y) * c.y;                              \
        d.z = beta.z * d.z + (1.f - beta.z) * c.z;                              \
        d.w = beta.w * d.w + (1.f - beta.w) * c.w;                              \
        float s4 = ((d.x + d.y) + d.z) + d.w;                                   \
        m = m * alpha + (1.f - alpha) * s4 - VTH_ * sp;                         \
        sp = (m > VTH_) ? 1.f : 0.f;                                            \
        SPIKE_STORE;                                                            \
    }                                                                           \
    ((float4*)dst)[idx] = d;                                                    \
    mst[idx] = m;                                                               \
    spst[idx] = sp;

__global__ __launch_bounds__(256)
void scan_i8_kernel(const float* __restrict__ cur, float* __restrict__ dst,
                    float* __restrict__ mst, float* __restrict__ spst,
                    int8_t* __restrict__ sout, const float* __restrict__ tau_m,
                    const float* __restrict__ tau_n, int tc) {
    SCAN_BODY(sout[((size_t)b * tc + t) * H_ + h] = (int8_t)(m > VTH_))
}

__global__ __launch_bounds__(256)
void scan_f16_kernel(const float* __restrict__ cur, float* __restrict__ dst,
                     float* __restrict__ mst, float* __restrict__ spst,
                     _Float16* __restrict__ sout, const float* __restrict__ tau_m,
                     const float* __restrict__ tau_n, int tc) {
    SCAN_BODY(sout[((size_t)b * tc + t) * H_ + h] = (_Float16)sp)
}

// ---------------- readout small GEMM: curo[b,t,o] = s2c[r,:] . Wo[o,:] + bo[o] ----------------
__global__ __launch_bounds__(256)
void rdot_kernel(const _Float16* __restrict__ s2c, const float* __restrict__ Wo,
                 const float* __restrict__ bo, float* __restrict__ curo, int t0, int tc) {
    int tid = blockIdx.x * 256 + threadIdx.x;   // (128*tc)*32 threads
    int r = tid >> 5;
    int n = tid & 31;
    if (n >= OUT_) return;
    const _Float16* a = s2c + (size_t)r * H_;
    const float*    w = Wo + (size_t)n * H_;
    float acc = bo[n];
    for (int k = 0; k < H_; k += 4) {
        acc += (float)a[k] * w[k] + (float)a[k + 1] * w[k + 1]
             + (float)a[k + 2] * w[k + 2] + (float)a[k + 3] * w[k + 3];
    }
    int bb = r / tc, tl = r - bb * tc;
    curo[((size_t)bb * T_ + t0 + tl) * OUT_ + n] = acc;
}

// ---------------- parallel readout: segmented scan + t-parallel softmax-sum ----------------
#define RT_SEG 12
#define RT_LEN 21   // 12*21 = 252 >= 250

__global__ __launch_bounds__(256)
void readout_kernel(const float* __restrict__ curo, const float* __restrict__ tau_mo,
                    float* __restrict__ out) {
    __shared__ float moS[T_ * OUT_];          // 20 KB
    __shared__ float segA[RT_SEG][OUT_];
    __shared__ float segU[RT_SEG][OUT_];
    __shared__ float pre[RT_SEG][OUT_];
    __shared__ float accS[OUT_];
    const int b = blockIdx.x;
    const int tid = threadIdx.x;
    const float* cb = curo + (size_t)b * T_ * OUT_;

    const int o = tid % OUT_;
    const int sg = tid / OUT_;
    const float ao = 1.f / (1.f + expf(-tau_mo[o]));

    if (tid < RT_SEG * OUT_) {
        int t0 = sg * RT_LEN;
        int t1 = min(T_, t0 + RT_LEN);
        float u = 0.f, Ap = 1.f;
        for (int t = t0; t < t1; t++) {
            u = ao * u + (1.f - ao) * cb[t * OUT_ + o];
            Ap *= ao;
        }
        segU[sg][o] = u; segA[sg][o] = Ap;
    }
    if (tid < OUT_) accS[tid] = 0.f;
    __syncthreads();
    if (tid < OUT_) {
        float m = 0.f;
        for (int s = 0; s < RT_SEG; s++) {
            pre[s][tid] = m;
            m = segA[s][tid] * m + segU[s][tid];
        }
    }
    __syncthreads();
    if (tid < RT_SEG * OUT_) {
        int t0 = sg * RT_LEN;
        int t1 = min(T_, t0 + RT_LEN);
        float m = pre[sg][o];
        for (int t = t0; t < t1; t++) {
            m = ao * m + (1.f - ao) * cb[t * OUT_ + o];
            moS[t * OUT_ + o] = m;
        }
    }
    __syncthreads();
    if (tid >= WARM_ + 1 && tid < T_) {
        int t = tid;
        float mx = -3.0e38f;
#pragma unroll
        for (int o2 = 0; o2 < OUT_; o2++) mx = fmaxf(mx, moS[t * OUT_ + o2]);
        float es[OUT_]; float se = 0.f;
#pragma unroll
        for (int o2 = 0; o2 < OUT_; o2++) {
            float e = expf(moS[t * OUT_ + o2] - mx);
            es[o2] = e; se += e;
        }
        float inv = 1.f / se;
#pragma unroll
        for (int o2 = 0; o2 < OUT_; o2++) atomicAdd(&accS[o2], es[o2] * inv);
    }
    __syncthreads();
    if (tid < OUT_) out[(size_t)b * OUT_ + tid] = accS[tid];
}

extern "C" void kernel_launch(void* const* d_in, const int* in_sizes, int n_in,
                              void* d_out, int out_size, void* d_ws, size_t ws_size,
                              hipStream_t stream) {
    const float* x      = (const float*)d_in[0];
    const float* W1     = (const float*)d_in[1];
    const float* b1     = (const float*)d_in[2];
    const float* tau_m1 = (const float*)d_in[3];
    const float* tau_n1 = (const float*)d_in[4];
    const float* mask1  = (const float*)d_in[5];
    const float* W2     = (const float*)d_in[6];
    const float* b2     = (const float*)d_in[7];
    const float* tau_m2 = (const float*)d_in[8];
    const float* tau_n2 = (const float*)d_in[9];
    const float* mask2  = (const float*)d_in[10];
    const float* Wo     = (const float*)d_in[11];
    const float* bo     = (const float*)d_in[12];
    const float* tau_mo = (const float*)d_in[13];
    float* out = (float*)d_out;

    char* p = (char*)d_ws;
    auto alloc = [&](size_t bytes) { char* r = p; p += (bytes + 255) & ~(size_t)255; return r; };
    _Float16* w10 = (_Float16*)alloc((size_t)HB_ * INP_ * 2);
    _Float16* w11 = (_Float16*)alloc((size_t)HB_ * INP_ * 2);
    int8_t*   q2  = (int8_t*)alloc((size_t)HB_ * H_);
    int8_t*   q1  = (int8_t*)alloc((size_t)HB_ * H_);
    int8_t*   q0  = (int8_t*)alloc((size_t)HB_ * H_);
    _Float16* xc0 = (_Float16*)alloc((size_t)B_ * TCMAX * INP_ * 2);
    _Float16* xc1 = (_Float16*)alloc((size_t)B_ * TCMAX * INP_ * 2);
    int8_t*   s1c = (int8_t*)alloc((size_t)B_ * TCMAX * H_);
    _Float16* s2c = (_Float16*)alloc((size_t)B_ * TCMAX * H_ * 2);
    float* cur    = (float*)alloc((size_t)B_ * TCMAX * HB_ * 4);
    float* curo   = (float*)alloc((size_t)B_ * T_ * OUT_ * 4);
    float* st     = (float*)alloc((size_t)786432 * 4);
    float* d1  = st;
    float* m1  = d1 + (size_t)B_ * H_ * BR_;
    float* sp1 = m1 + (size_t)B_ * H_;
    float* d2  = sp1 + (size_t)B_ * H_;
    float* m2  = d2 + (size_t)B_ * H_ * BR_;
    float* sp2 = m2 + (size_t)B_ * H_;

    w1prep_kernel<<<(HB_ * INP_ + 255) / 256, 256, 0, stream>>>(W1, mask1, w10, w11);
    w2prep_kernel<<<(HB_ * H_ + 255) / 256, 256, 0, stream>>>(W2, mask2, q2, q1, q0);
    zero_kernel<<<(786432 / 4 + 255) / 256, 256, 0, stream>>>(st, 786432 / 4);

    const int tcs[3] = {100, 100, 50};
    int t0 = 0;
    for (int c = 0; c < 3; c++) {
        const int tc = tcs[c];
        const int M = B_ * tc;                 // rows this chunk (mult of 128)
        dim3 gg(HB_ / 128, M / 128);
        convx_kernel<<<(M * INP_ + 255) / 256, 256, 0, stream>>>(x, xc0, xc1, t0, tc, M * INP_);
        l1_gemm_kernel<<<gg, 256, 0, stream>>>(xc0, xc1, w10, w11, b1, cur);
        scan_i8_kernel<<<B_ * H_ / 256, 256, 0, stream>>>(cur, d1, m1, sp1, s1c, tau_m1, tau_n1, tc);
        mfma_i8_gemm_kernel<<<gg, 256, 0, stream>>>(s1c, q2, q1, q0, b2, cur);
        scan_f16_kernel<<<B_ * H_ / 256, 256, 0, stream>>>(cur, d2, m2, sp2, s2c, tau_m2, tau_n2, tc);
        rdot_kernel<<<(M * 32) / 256, 256, 0, stream>>>(s2c, Wo, bo, curo, t0, tc);
        t0 += tc;
    }
    readout_kernel<<<B_, 256, 0, stream>>>(curo, tau_mo, out);
}

// Round 5
// 1068.220 us; speedup vs baseline: 2.3018x; 1.0440x over previous
//
#include <hip/hip_runtime.h>
#include <math.h>
#include <stdint.h>

// Problem dims
#define B_    128
#define T_    250
#define IN_   700
#define INP_  704    // padded to 32
#define H_    512
#define OUT_  20
#define BR_   4
#define HB_   2048   // H_*BR_
#define TCMAX 125    // time chunk (2 chunks of 125)
#define WARM_ 10
#define VTH_  1.0f

typedef __attribute__((ext_vector_type(8))) _Float16 half8;
typedef __attribute__((ext_vector_type(4))) float f32x4;
typedef __attribute__((ext_vector_type(4))) int i32x4;
typedef const __attribute__((address_space(1))) void* gptr_t;
typedef __attribute__((address_space(3))) void* lptr_t;

// ---------------- prep: split fp32 -> hi/lo fp16 planes (layer 1) ----------------
__global__ __launch_bounds__(256)
void w1prep_kernel(const float* __restrict__ W, const float* __restrict__ M,
                   _Float16* __restrict__ w0, _Float16* __restrict__ w1) {
    int i = blockIdx.x * 256 + threadIdx.x;           // over HB_*INP_
    if (i >= HB_ * INP_) return;
    int r = i / INP_, c = i - r * INP_;
    float v = (c < IN_) ? W[(size_t)r * IN_ + c] * M[(size_t)r * IN_ + c] : 0.f;
    _Float16 h0 = (_Float16)v;
    w0[i] = h0;
    w1[i] = (_Float16)(v - (float)h0);
}

// ---------------- prep: layer-2 weights -> 3 signed radix-256 i8 planes, scale 2^26 ----------------
__global__ __launch_bounds__(256)
void w2prep_kernel(const float* __restrict__ W, const float* __restrict__ M,
                   int8_t* __restrict__ p2, int8_t* __restrict__ p1,
                   int8_t* __restrict__ p0) {
    int i = blockIdx.x * 256 + threadIdx.x;           // over HB_*H_
    if (i >= HB_ * H_) return;
    float v = W[i] * M[i];
    int q = (int)lrintf(v * 67108864.f);              // |q| <= 0.0442*2^26 ~ 2.97e6
    int b0 = (int)(int8_t)(q & 0xFF);  q = (q - b0) >> 8;
    int b1 = (int)(int8_t)(q & 0xFF);  int b2 = (q - b1) >> 8;   // |b2| <= 46
    p0[i] = (int8_t)b0; p1[i] = (int8_t)b1; p2[i] = (int8_t)b2;
}

__global__ void zero_kernel(float* __restrict__ p, int n4) {
    int i = blockIdx.x * blockDim.x + threadIdx.x;
    if (i < n4) ((float4*)p)[i] = make_float4(0.f, 0.f, 0.f, 0.f);
}

// ---------------- L1 GEMM: raw-x inline fp16-split, 3 products in one acc ----------------
// C[m,n] = x[m,:].w[n,:] + bias[n]; x raw [B,T,IN], chunk row r -> (r/tc, t0 + r%tc)
__global__ __launch_bounds__(256)
void l1_gemm_kernel(const float* __restrict__ x,
                    const _Float16* __restrict__ w0, const _Float16* __restrict__ w1,
                    const float* __restrict__ bias, float* __restrict__ C,
                    int t0, int tc) {
    __shared__ alignas(16) _Float16 A0s[128 * 32];
    __shared__ alignas(16) _Float16 A1s[128 * 32];
    __shared__ alignas(16) _Float16 B0s[128 * 32];
    __shared__ alignas(16) _Float16 B1s[128 * 32];
    const int tid  = threadIdx.x;
    const int wave = tid >> 6, lane = tid & 63;
    const int bm = blockIdx.y * 128, bn = blockIdx.x * 128;

    const int srow  = tid >> 2;           // 0..63
    const int skoff = (tid & 3) * 8;      // 0,8,16,24 (elements)

    // A global row pointers (chunk mapping) for rows srow and srow+64
    const int r0 = bm + srow;
    const int bb0 = r0 / tc, tl0 = r0 - bb0 * tc;
    const float* xr0 = x + ((size_t)bb0 * T_ + t0 + tl0) * IN_;
    const int r1 = r0 + 64;
    const int bb1 = r1 / tc, tl1 = r1 - bb1 * tc;
    const float* xr1 = x + ((size_t)bb1 * T_ + t0 + tl1) * IN_;

    // B staging (async direct-to-LDS)
    const size_t boff0 = (size_t)(bn + srow) * INP_ + skoff;
    const size_t boff1 = boff0 + (size_t)64 * INP_;
    const int lo0 = wave * 512, lo1 = 2048 + wave * 512;

    // A ds_write addresses (halfs)
    _Float16* a0w0 = A0s + srow * 32 + skoff;
    _Float16* a0w1 = a0w0 + 64 * 32;
    _Float16* a1w0 = A1s + srow * 32 + skoff;
    _Float16* a1w1 = a1w0 + 64 * 32;

    const int wm = wave & 1, wn = wave >> 1;
    const int fr = lane & 15;
    const int fk = (lane >> 4) * 8;

    f32x4 acc[4][4] = {};

    for (int kt = 0; kt < INP_ / 32; kt++) {
        const int k0 = kt * 32;
        __builtin_amdgcn_global_load_lds((gptr_t)(w0 + boff0 + k0), (lptr_t)(B0s + lo0), 16, 0, 0);
        __builtin_amdgcn_global_load_lds((gptr_t)(w0 + boff1 + k0), (lptr_t)(B0s + lo1), 16, 0, 0);
        __builtin_amdgcn_global_load_lds((gptr_t)(w1 + boff0 + k0), (lptr_t)(B1s + lo0), 16, 0, 0);
        __builtin_amdgcn_global_load_lds((gptr_t)(w1 + boff1 + k0), (lptr_t)(B1s + lo1), 16, 0, 0);

        // A: load fp32, split to hi/lo fp16, write to LDS
        const int c0 = k0 + skoff;
        const bool vf1 = (c0 + 8 <= IN_);          // only last tile's (tid&3)==3 fails
        float4 f0a = *(const float4*)(xr0 + c0);   // c0+4 <= 700 always
        float4 f1a = vf1 ? *(const float4*)(xr0 + c0 + 4) : make_float4(0.f, 0.f, 0.f, 0.f);
        float4 f0b = *(const float4*)(xr1 + c0);
        float4 f1b = vf1 ? *(const float4*)(xr1 + c0 + 4) : make_float4(0.f, 0.f, 0.f, 0.f);

        half8 h0a, h1a, h0b, h1b;
        const float* fa = (const float*)&f0a;      // f0a,f1a contiguous? no — handle explicitly
        {
            float v[8] = {f0a.x, f0a.y, f0a.z, f0a.w, f1a.x, f1a.y, f1a.z, f1a.w};
#pragma unroll
            for (int j = 0; j < 8; j++) {
                _Float16 h = (_Float16)v[j];
                h0a[j] = h; h1a[j] = (_Float16)(v[j] - (float)h);
            }
        }
        {
            float v[8] = {f0b.x, f0b.y, f0b.z, f0b.w, f1b.x, f1b.y, f1b.z, f1b.w};
#pragma unroll
            for (int j = 0; j < 8; j++) {
                _Float16 h = (_Float16)v[j];
                h0b[j] = h; h1b[j] = (_Float16)(v[j] - (float)h);
            }
        }
        (void)fa;
        *(half8*)a0w0 = h0a; *(half8*)a1w0 = h1a;
        *(half8*)a0w1 = h0b; *(half8*)a1w1 = h1b;
        __syncthreads();

        half8 a0[4], a1[4], b0[4], b1[4];
#pragma unroll
        for (int mi = 0; mi < 4; mi++)
            a0[mi] = *(const half8*)&A0s[(wm * 64 + mi * 16 + fr) * 32 + fk];
#pragma unroll
        for (int ni = 0; ni < 4; ni++)
            b0[ni] = *(const half8*)&B0s[(wn * 64 + ni * 16 + fr) * 32 + fk];
#pragma unroll
        for (int mi = 0; mi < 4; mi++)
#pragma unroll
            for (int ni = 0; ni < 4; ni++)
                acc[mi][ni] = __builtin_amdgcn_mfma_f32_16x16x32_f16(a0[mi], b0[ni], acc[mi][ni], 0, 0, 0);
#pragma unroll
        for (int ni = 0; ni < 4; ni++)
            b1[ni] = *(const half8*)&B1s[(wn * 64 + ni * 16 + fr) * 32 + fk];
#pragma unroll
        for (int mi = 0; mi < 4; mi++)
#pragma unroll
            for (int ni = 0; ni < 4; ni++)
                acc[mi][ni] = __builtin_amdgcn_mfma_f32_16x16x32_f16(a0[mi], b1[ni], acc[mi][ni], 0, 0, 0);
#pragma unroll
        for (int mi = 0; mi < 4; mi++)
            a1[mi] = *(const half8*)&A1s[(wm * 64 + mi * 16 + fr) * 32 + fk];
#pragma unroll
        for (int mi = 0; mi < 4; mi++)
#pragma unroll
            for (int ni = 0; ni < 4; ni++)
                acc[mi][ni] = __builtin_amdgcn_mfma_f32_16x16x32_f16(a1[mi], b0[ni], acc[mi][ni], 0, 0, 0);
        __syncthreads();
    }

    const int cc = lane & 15;
    const int cr = (lane >> 4) * 4;
#pragma unroll
    for (int ni = 0; ni < 4; ni++) {
        const int gc = bn + wn * 64 + ni * 16 + cc;
        const float bv = bias[gc];
#pragma unroll
        for (int mi = 0; mi < 4; mi++) {
            const int gr = bm + wm * 64 + mi * 16 + cr;
            float* cp = C + (size_t)gr * HB_ + gc;
#pragma unroll
            for (int r = 0; r < 4; r++) cp[(size_t)r * HB_] = acc[mi][ni][r] + bv;
        }
    }
}

// ---------------- i8 fixed-point MFMA GEMM (layer 2): exact Horner over 3 planes ----------------
__global__ __launch_bounds__(256)
void mfma_i8_gemm_kernel(const int8_t* __restrict__ A,
                         const int8_t* __restrict__ p2, const int8_t* __restrict__ p1,
                         const int8_t* __restrict__ p0,
                         const float* __restrict__ bias, float* __restrict__ C) {
    __shared__ alignas(16) int8_t As[128 * 64];   // 8 KB, K-tile 64
    __shared__ alignas(16) int8_t Bs[128 * 64];
    const int tid  = threadIdx.x;
    const int wave = tid >> 6, lane = tid & 63;
    const int bm = blockIdx.y * 128, bn = blockIdx.x * 128;

    const int    srow  = tid >> 2;
    const int    skoff = (tid & 3) * 16;
    const size_t aoff0 = (size_t)(bm + srow) * H_ + skoff;
    const size_t aoff1 = aoff0 + (size_t)64 * H_;
    const size_t boff0 = (size_t)(bn + srow) * H_ + skoff;
    const size_t boff1 = boff0 + (size_t)64 * H_;
    lptr_t lA0 = (lptr_t)(As + wave * 1024);
    lptr_t lA1 = (lptr_t)(As + 4096 + wave * 1024);
    lptr_t lB0 = (lptr_t)(Bs + wave * 1024);
    lptr_t lB1 = (lptr_t)(Bs + 4096 + wave * 1024);

    const int wm = wave & 1, wn = wave >> 1;
    const int fr = lane & 15;
    const int fk = (lane >> 4) * 16;

    const int8_t* planes[3] = {p2, p1, p0};
    i32x4 acc[4][4] = {};

#pragma unroll
    for (int s = 0; s < 3; s++) {
        if (s) {
#pragma unroll
            for (int mi = 0; mi < 4; mi++)
#pragma unroll
                for (int ni = 0; ni < 4; ni++) acc[mi][ni] *= 256;  // exact, |acc|<1.6e9
        }
        const int8_t* pw = planes[s];
        for (int kt = 0; kt < H_ / 64; kt++) {
            const int k0 = kt * 64;
            __builtin_amdgcn_global_load_lds((gptr_t)(A  + aoff0 + k0), lA0, 16, 0, 0);
            __builtin_amdgcn_global_load_lds((gptr_t)(A  + aoff1 + k0), lA1, 16, 0, 0);
            __builtin_amdgcn_global_load_lds((gptr_t)(pw + boff0 + k0), lB0, 16, 0, 0);
            __builtin_amdgcn_global_load_lds((gptr_t)(pw + boff1 + k0), lB1, 16, 0, 0);
            __syncthreads();

            i32x4 af[4], bf[4];
#pragma unroll
            for (int mi = 0; mi < 4; mi++)
                af[mi] = *(const i32x4*)&As[(wm * 64 + mi * 16 + fr) * 64 + fk];
#pragma unroll
            for (int ni = 0; ni < 4; ni++)
                bf[ni] = *(const i32x4*)&Bs[(wn * 64 + ni * 16 + fr) * 64 + fk];
#pragma unroll
            for (int mi = 0; mi < 4; mi++)
#pragma unroll
                for (int ni = 0; ni < 4; ni++)
                    acc[mi][ni] = __builtin_amdgcn_mfma_i32_16x16x64_i8(
                        af[mi], bf[ni], acc[mi][ni], 0, 0, 0);
            __syncthreads();
        }
    }

    const float scale = 1.f / 67108864.f;
    const int cc = lane & 15;
    const int cr = (lane >> 4) * 4;
#pragma unroll
    for (int ni = 0; ni < 4; ni++) {
        const int gc = bn + wn * 64 + ni * 16 + cc;
        const float bv = bias[gc];
#pragma unroll
        for (int mi = 0; mi < 4; mi++) {
            const int gr = bm + wm * 64 + mi * 16 + cr;
            float* cp = C + (size_t)gr * HB_ + gc;
#pragma unroll
            for (int r = 0; r < 4; r++)
                cp[(size_t)r * HB_] = (float)acc[mi][ni][r] * scale + bv;
        }
    }
}

// ---------------- per-(b,h) LIF scans over a time chunk (chunk-local I/O) ----------------
#define SCAN_BODY(SPIKE_STORE)                                                  \
    int idx = blockIdx.x * 256 + threadIdx.x;                                   \
    int b = idx >> 9;                                                           \
    int h = idx & (H_ - 1);                                                     \
    float alpha = 1.f / (1.f + expf(-tau_m[h]));                                \
    float4 tn = ((const float4*)tau_n)[h];                                      \
    float4 beta;                                                                \
    beta.x = 1.f / (1.f + expf(-tn.x));                                         \
    beta.y = 1.f / (1.f + expf(-tn.y));                                         \
    beta.z = 1.f / (1.f + expf(-tn.z));                                         \
    beta.w = 1.f / (1.f + expf(-tn.w));                                         \
    float4 d = ((const float4*)dst)[idx];                                       \
    float m = mst[idx];                                                         \
    float sp = spst[idx];                                                       \
    const float* cp = cur + (size_t)b * tc * HB_ + h * BR_;                     \
    for (int t = 0; t < tc; t++) {                                              \
        float4 c = *(const float4*)cp;                                          \
        cp += HB_;                                                              \
        d.x = beta.x * d.x + (1.f - beta.x) * c.x;                              \
        d.y = beta.y * d.y + (1.f - beta.y) * c.y;                              \
        d.z = beta.z * d.z + (1.f - beta.z) * c.z;                              \
        d.w = beta.w * d.w + (1.f - beta.w) * c.w;                              \
        float s4 = ((d.x + d.y) + d.z) + d.w;                                   \
        m = m * alpha + (1.f - alpha) * s4 - VTH_ * sp;                         \
        sp = (m > VTH_) ? 1.f : 0.f;                                            \
        SPIKE_STORE;                                                            \
    }                                                                           \
    ((float4*)dst)[idx] = d;                                                    \
    mst[idx] = m;                                                               \
    spst[idx] = sp;

__global__ __launch_bounds__(256)
void scan_i8_kernel(const float* __restrict__ cur, float* __restrict__ dst,
                    float* __restrict__ mst, float* __restrict__ spst,
                    int8_t* __restrict__ sout, const float* __restrict__ tau_m,
                    const float* __restrict__ tau_n, int tc) {
    SCAN_BODY(sout[((size_t)b * tc + t) * H_ + h] = (int8_t)(m > VTH_))
}

__global__ __launch_bounds__(256)
void scan_f16_kernel(const float* __restrict__ cur, float* __restrict__ dst,
                     float* __restrict__ mst, float* __restrict__ spst,
                     _Float16* __restrict__ sout, const float* __restrict__ tau_m,
                     const float* __restrict__ tau_n, int tc) {
    SCAN_BODY(sout[((size_t)b * tc + t) * H_ + h] = (_Float16)sp)
}

// ---------------- readout small GEMM: curo[b,t,o] = s2c[r,:] . Wo[o,:] + bo[o] ----------------
__global__ __launch_bounds__(256)
void rdot_kernel(const _Float16* __restrict__ s2c, const float* __restrict__ Wo,
                 const float* __restrict__ bo, float* __restrict__ curo, int t0, int tc) {
    int tid = blockIdx.x * 256 + threadIdx.x;   // (128*tc)*32 threads
    int r = tid >> 5;
    int n = tid & 31;
    if (n >= OUT_) return;
    const _Float16* a = s2c + (size_t)r * H_;
    const float*    w = Wo + (size_t)n * H_;
    float acc = bo[n];
    for (int k = 0; k < H_; k += 4) {
        acc += (float)a[k] * w[k] + (float)a[k + 1] * w[k + 1]
             + (float)a[k + 2] * w[k + 2] + (float)a[k + 3] * w[k + 3];
    }
    int bb = r / tc, tl = r - bb * tc;
    curo[((size_t)bb * T_ + t0 + tl) * OUT_ + n] = acc;
}

// ---------------- parallel readout: segmented scan + t-parallel softmax-sum ----------------
#define RT_SEG 12
#define RT_LEN 21   // 12*21 = 252 >= 250

__global__ __launch_bounds__(256)
void readout_kernel(const float* __restrict__ curo, const float* __restrict__ tau_mo,
                    float* __restrict__ out) {
    __shared__ float moS[T_ * OUT_];          // 20 KB
    __shared__ float segA[RT_SEG][OUT_];
    __shared__ float segU[RT_SEG][OUT_];
    __shared__ float pre[RT_SEG][OUT_];
    __shared__ float accS[OUT_];
    const int b = blockIdx.x;
    const int tid = threadIdx.x;
    const float* cb = curo + (size_t)b * T_ * OUT_;

    const int o = tid % OUT_;
    const int sg = tid / OUT_;
    const float ao = 1.f / (1.f + expf(-tau_mo[o]));

    if (tid < RT_SEG * OUT_) {
        int t0 = sg * RT_LEN;
        int t1 = min(T_, t0 + RT_LEN);
        float u = 0.f, Ap = 1.f;
        for (int t = t0; t < t1; t++) {
            u = ao * u + (1.f - ao) * cb[t * OUT_ + o];
            Ap *= ao;
        }
        segU[sg][o] = u; segA[sg][o] = Ap;
    }
    if (tid < OUT_) accS[tid] = 0.f;
    __syncthreads();
    if (tid < OUT_) {
        float m = 0.f;
        for (int s = 0; s < RT_SEG; s++) {
            pre[s][tid] = m;
            m = segA[s][tid] * m + segU[s][tid];
        }
    }
    __syncthreads();
    if (tid < RT_SEG * OUT_) {
        int t0 = sg * RT_LEN;
        int t1 = min(T_, t0 + RT_LEN);
        float m = pre[sg][o];
        for (int t = t0; t < t1; t++) {
            m = ao * m + (1.f - ao) * cb[t * OUT_ + o];
            moS[t * OUT_ + o] = m;
        }
    }
    __syncthreads();
    if (tid >= WARM_ + 1 && tid < T_) {
        int t = tid;
        float mx = -3.0e38f;
#pragma unroll
        for (int o2 = 0; o2 < OUT_; o2++) mx = fmaxf(mx, moS[t * OUT_ + o2]);
        float es[OUT_]; float se = 0.f;
#pragma unroll
        for (int o2 = 0; o2 < OUT_; o2++) {
            float e = expf(moS[t * OUT_ + o2] - mx);
            es[o2] = e; se += e;
        }
        float inv = 1.f / se;
#pragma unroll
        for (int o2 = 0; o2 < OUT_; o2++) atomicAdd(&accS[o2], es[o2] * inv);
    }
    __syncthreads();
    if (tid < OUT_) out[(size_t)b * OUT_ + tid] = accS[tid];
}

extern "C" void kernel_launch(void* const* d_in, const int* in_sizes, int n_in,
                              void* d_out, int out_size, void* d_ws, size_t ws_size,
                              hipStream_t stream) {
    const float* x      = (const float*)d_in[0];
    const float* W1     = (const float*)d_in[1];
    const float* b1     = (const float*)d_in[2];
    const float* tau_m1 = (const float*)d_in[3];
    const float* tau_n1 = (const float*)d_in[4];
    const float* mask1  = (const float*)d_in[5];
    const float* W2     = (const float*)d_in[6];
    const float* b2     = (const float*)d_in[7];
    const float* tau_m2 = (const float*)d_in[8];
    const float* tau_n2 = (const float*)d_in[9];
    const float* mask2  = (const float*)d_in[10];
    const float* Wo     = (const float*)d_in[11];
    const float* bo     = (const float*)d_in[12];
    const float* tau_mo = (const float*)d_in[13];
    float* out = (float*)d_out;

    char* p = (char*)d_ws;
    auto alloc = [&](size_t bytes) { char* r = p; p += (bytes + 255) & ~(size_t)255; return r; };
    _Float16* w10 = (_Float16*)alloc((size_t)HB_ * INP_ * 2);
    _Float16* w11 = (_Float16*)alloc((size_t)HB_ * INP_ * 2);
    int8_t*   q2  = (int8_t*)alloc((size_t)HB_ * H_);
    int8_t*   q1  = (int8_t*)alloc((size_t)HB_ * H_);
    int8_t*   q0  = (int8_t*)alloc((size_t)HB_ * H_);
    int8_t*   s1c = (int8_t*)alloc((size_t)B_ * TCMAX * H_);
    _Float16* s2c = (_Float16*)alloc((size_t)B_ * TCMAX * H_ * 2);
    float* cur    = (float*)alloc((size_t)B_ * TCMAX * HB_ * 4);
    float* curo   = (float*)alloc((size_t)B_ * T_ * OUT_ * 4);
    float* st     = (float*)alloc((size_t)786432 * 4);
    float* d1  = st;
    float* m1  = d1 + (size_t)B_ * H_ * BR_;
    float* sp1 = m1 + (size_t)B_ * H_;
    float* d2  = sp1 + (size_t)B_ * H_;
    float* m2  = d2 + (size_t)B_ * H_ * BR_;
    float* sp2 = m2 + (size_t)B_ * H_;

    w1prep_kernel<<<(HB_ * INP_ + 255) / 256, 256, 0, stream>>>(W1, mask1, w10, w11);
    w2prep_kernel<<<(HB_ * H_ + 255) / 256, 256, 0, stream>>>(W2, mask2, q2, q1, q0);
    zero_kernel<<<(786432 / 4 + 255) / 256, 256, 0, stream>>>(st, 786432 / 4);

    const int tcs[2] = {125, 125};
    int t0 = 0;
    for (int c = 0; c < 2; c++) {
        const int tc = tcs[c];
        const int M = B_ * tc;                 // 16000, mult of 128
        dim3 gg(HB_ / 128, M / 128);           // (16, 125)
        l1_gemm_kernel<<<gg, 256, 0, stream>>>(x, w10, w11, b1, cur, t0, tc);
        scan_i8_kernel<<<B_ * H_ / 256, 256, 0, stream>>>(cur, d1, m1, sp1, s1c, tau_m1, tau_n1, tc);
        mfma_i8_gemm_kernel<<<gg, 256, 0, stream>>>(s1c, q2, q1, q0, b2, cur);
        scan_f16_kernel<<<B_ * H_ / 256, 256, 0, stream>>>(cur, d2, m2, sp2, s2c, tau_m2, tau_n2, tc);
        rdot_kernel<<<(M * 32) / 256, 256, 0, stream>>>(s2c, Wo, bo, curo, t0, tc);
        t0 += tc;
    }
    readout_kernel<<<B_, 256, 0, stream>>>(curo, tau_mo, out);
}

// Round 6
// 925.521 us; speedup vs baseline: 2.6567x; 1.1542x over previous
//
#include <hip/hip_runtime.h>
#include <math.h>
#include <stdint.h>

// Problem dims
#define B_    128
#define T_    250
#define IN_   700
#define INP_  704    // padded to 32
#define H_    512
#define OUT_  20
#define BR_   4
#define HB_   2048   // H_*BR_
#define WARM_ 10
#define VTH_  1.0f

typedef __attribute__((ext_vector_type(8))) _Float16 half8;
typedef __attribute__((ext_vector_type(4))) float f32x4;
typedef __attribute__((ext_vector_type(4))) int i32x4;
typedef const __attribute__((address_space(1))) void* gptr_t;
typedef __attribute__((address_space(3))) void* lptr_t;

// ---------------- prep: split fp32 -> hi/lo fp16 planes (layer 1) ----------------
__global__ __launch_bounds__(256)
void w1prep_kernel(const float* __restrict__ W, const float* __restrict__ M,
                   _Float16* __restrict__ w0, _Float16* __restrict__ w1) {
    int i = blockIdx.x * 256 + threadIdx.x;           // over HB_*INP_
    if (i >= HB_ * INP_) return;
    int r = i / INP_, c = i - r * INP_;
    float v = (c < IN_) ? W[(size_t)r * IN_ + c] * M[(size_t)r * IN_ + c] : 0.f;
    _Float16 h0 = (_Float16)v;
    w0[i] = h0;
    w1[i] = (_Float16)(v - (float)h0);
}

// ---------------- prep: layer-2 weights -> 3 signed radix-256 i8 planes, scale 2^26 ----------------
__global__ __launch_bounds__(256)
void w2prep_kernel(const float* __restrict__ W, const float* __restrict__ M,
                   int8_t* __restrict__ p2, int8_t* __restrict__ p1,
                   int8_t* __restrict__ p0) {
    int i = blockIdx.x * 256 + threadIdx.x;           // over HB_*H_
    if (i >= HB_ * H_) return;
    float v = W[i] * M[i];
    int q = (int)lrintf(v * 67108864.f);              // |q| <= 0.0442*2^26 ~ 2.97e6
    int b0 = (int)(int8_t)(q & 0xFF);  q = (q - b0) >> 8;
    int b1 = (int)(int8_t)(q & 0xFF);  int b2 = (q - b1) >> 8;   // |b2| <= 46
    p0[i] = (int8_t)b0; p1[i] = (int8_t)b1; p2[i] = (int8_t)b2;
}

// ---------------- prep: readout weights -> hi/lo fp16 planes, n padded to 32 ----------------
__global__ __launch_bounds__(256)
void woprep_kernel(const float* __restrict__ Wo, _Float16* __restrict__ wo0,
                   _Float16* __restrict__ wo1) {
    int i = blockIdx.x * 256 + threadIdx.x;           // over 32*H_
    if (i >= 32 * H_) return;
    int n = i >> 9;
    float v = (n < OUT_) ? Wo[(size_t)n * H_ + (i & (H_ - 1))] : 0.f;
    _Float16 h0 = (_Float16)v;
    wo0[i] = h0;
    wo1[i] = (_Float16)(v - (float)h0);
}

// per-chunk x conversion: global rows (bb*T_+t0+tl) -> chunk-local [128*tc, INP_]
__global__ __launch_bounds__(256)
void convx_kernel(const float* __restrict__ x, _Float16* __restrict__ x0,
                  _Float16* __restrict__ x1, int t0, int tc, int ntot) {
    int i = blockIdx.x * 256 + threadIdx.x;
    if (i >= ntot) return;
    int r = i / INP_, c = i - r * INP_;
    int bb = r / tc, tl = r - bb * tc;
    float v = (c < IN_) ? x[((size_t)bb * T_ + t0 + tl) * IN_ + c] : 0.f;
    _Float16 h0 = (_Float16)v;
    x0[i] = h0;
    x1[i] = (_Float16)(v - (float)h0);
}

__global__ void zero_kernel(float* __restrict__ p, int n4) {
    int i = blockIdx.x * blockDim.x + threadIdx.x;
    if (i < n4) ((float4*)p)[i] = make_float4(0.f, 0.f, 0.f, 0.f);
}

// ---------------- L1 GEMM: k-major, 3 products (x0w0 + x0w1 + x1w0), m-fastest grid ----------------
__global__ __launch_bounds__(256)
void l1_gemm_kernel(const _Float16* __restrict__ x0, const _Float16* __restrict__ x1,
                    const _Float16* __restrict__ w0, const _Float16* __restrict__ w1,
                    const float* __restrict__ bias, float* __restrict__ C) {
    __shared__ alignas(16) _Float16 A0s[128 * 32];
    __shared__ alignas(16) _Float16 A1s[128 * 32];
    __shared__ alignas(16) _Float16 B0s[128 * 32];
    __shared__ alignas(16) _Float16 B1s[128 * 32];
    const int tid  = threadIdx.x;
    const int wave = tid >> 6, lane = tid & 63;
    const int bm = blockIdx.x * 128, bn = blockIdx.y * 128;   // m-fastest for L2 weight reuse

    const int    srow  = tid >> 2;
    const int    skoff = (tid & 3) * 8;
    const size_t aoff0 = (size_t)(bm + srow) * INP_ + skoff;
    const size_t aoff1 = aoff0 + (size_t)64 * INP_;
    const size_t boff0 = (size_t)(bn + srow) * INP_ + skoff;
    const size_t boff1 = boff0 + (size_t)64 * INP_;
    const int lo0 = wave * 512, lo1 = 2048 + wave * 512;

    const int wm = wave & 1, wn = wave >> 1;
    const int fr = lane & 15;
    const int fk = (lane >> 4) * 8;

    f32x4 acc[4][4] = {};

    for (int kt = 0; kt < INP_ / 32; kt++) {
        const int k0 = kt * 32;
        __builtin_amdgcn_global_load_lds((gptr_t)(x0 + aoff0 + k0), (lptr_t)(A0s + lo0), 16, 0, 0);
        __builtin_amdgcn_global_load_lds((gptr_t)(x0 + aoff1 + k0), (lptr_t)(A0s + lo1), 16, 0, 0);
        __builtin_amdgcn_global_load_lds((gptr_t)(x1 + aoff0 + k0), (lptr_t)(A1s + lo0), 16, 0, 0);
        __builtin_amdgcn_global_load_lds((gptr_t)(x1 + aoff1 + k0), (lptr_t)(A1s + lo1), 16, 0, 0);
        __builtin_amdgcn_global_load_lds((gptr_t)(w0 + boff0 + k0), (lptr_t)(B0s + lo0), 16, 0, 0);
        __builtin_amdgcn_global_load_lds((gptr_t)(w0 + boff1 + k0), (lptr_t)(B0s + lo1), 16, 0, 0);
        __builtin_amdgcn_global_load_lds((gptr_t)(w1 + boff0 + k0), (lptr_t)(B1s + lo0), 16, 0, 0);
        __builtin_amdgcn_global_load_lds((gptr_t)(w1 + boff1 + k0), (lptr_t)(B1s + lo1), 16, 0, 0);
        __syncthreads();

        half8 a0[4], a1[4], b0[4], b1[4];
#pragma unroll
        for (int mi = 0; mi < 4; mi++)
            a0[mi] = *(const half8*)&A0s[(wm * 64 + mi * 16 + fr) * 32 + fk];
#pragma unroll
        for (int ni = 0; ni < 4; ni++)
            b0[ni] = *(const half8*)&B0s[(wn * 64 + ni * 16 + fr) * 32 + fk];
#pragma unroll
        for (int mi = 0; mi < 4; mi++)
#pragma unroll
            for (int ni = 0; ni < 4; ni++)
                acc[mi][ni] = __builtin_amdgcn_mfma_f32_16x16x32_f16(a0[mi], b0[ni], acc[mi][ni], 0, 0, 0);
#pragma unroll
        for (int ni = 0; ni < 4; ni++)
            b1[ni] = *(const half8*)&B1s[(wn * 64 + ni * 16 + fr) * 32 + fk];
#pragma unroll
        for (int mi = 0; mi < 4; mi++)
#pragma unroll
            for (int ni = 0; ni < 4; ni++)
                acc[mi][ni] = __builtin_amdgcn_mfma_f32_16x16x32_f16(a0[mi], b1[ni], acc[mi][ni], 0, 0, 0);
#pragma unroll
        for (int mi = 0; mi < 4; mi++)
            a1[mi] = *(const half8*)&A1s[(wm * 64 + mi * 16 + fr) * 32 + fk];
#pragma unroll
        for (int mi = 0; mi < 4; mi++)
#pragma unroll
            for (int ni = 0; ni < 4; ni++)
                acc[mi][ni] = __builtin_amdgcn_mfma_f32_16x16x32_f16(a1[mi], b0[ni], acc[mi][ni], 0, 0, 0);
        __syncthreads();
    }

    const int cc = lane & 15;
    const int cr = (lane >> 4) * 4;
#pragma unroll
    for (int ni = 0; ni < 4; ni++) {
        const int gc = bn + wn * 64 + ni * 16 + cc;
        const float bv = bias[gc];
#pragma unroll
        for (int mi = 0; mi < 4; mi++) {
            const int gr = bm + wm * 64 + mi * 16 + cr;
            float* cp = C + (size_t)gr * HB_ + gc;
#pragma unroll
            for (int r = 0; r < 4; r++) cp[(size_t)r * HB_] = acc[mi][ni][r] + bv;
        }
    }
}

// ---------------- i8 fixed-point MFMA GEMM (layer 2): exact Horner, m-fastest grid ----------------
__global__ __launch_bounds__(256)
void mfma_i8_gemm_kernel(const int8_t* __restrict__ A,
                         const int8_t* __restrict__ p2, const int8_t* __restrict__ p1,
                         const int8_t* __restrict__ p0,
                         const float* __restrict__ bias, float* __restrict__ C) {
    __shared__ alignas(16) int8_t As[128 * 64];   // 8 KB, K-tile 64
    __shared__ alignas(16) int8_t Bs[128 * 64];
    const int tid  = threadIdx.x;
    const int wave = tid >> 6, lane = tid & 63;
    const int bm = blockIdx.x * 128, bn = blockIdx.y * 128;   // m-fastest

    const int    srow  = tid >> 2;
    const int    skoff = (tid & 3) * 16;
    const size_t aoff0 = (size_t)(bm + srow) * H_ + skoff;
    const size_t aoff1 = aoff0 + (size_t)64 * H_;
    const size_t boff0 = (size_t)(bn + srow) * H_ + skoff;
    const size_t boff1 = boff0 + (size_t)64 * H_;
    lptr_t lA0 = (lptr_t)(As + wave * 1024);
    lptr_t lA1 = (lptr_t)(As + 4096 + wave * 1024);
    lptr_t lB0 = (lptr_t)(Bs + wave * 1024);
    lptr_t lB1 = (lptr_t)(Bs + 4096 + wave * 1024);

    const int wm = wave & 1, wn = wave >> 1;
    const int fr = lane & 15;
    const int fk = (lane >> 4) * 16;

    const int8_t* planes[3] = {p2, p1, p0};
    i32x4 acc[4][4] = {};

#pragma unroll
    for (int s = 0; s < 3; s++) {
        if (s) {
#pragma unroll
            for (int mi = 0; mi < 4; mi++)
#pragma unroll
                for (int ni = 0; ni < 4; ni++) acc[mi][ni] *= 256;  // exact, |acc|<1.6e9
        }
        const int8_t* pw = planes[s];
        for (int kt = 0; kt < H_ / 64; kt++) {
            const int k0 = kt * 64;
            __builtin_amdgcn_global_load_lds((gptr_t)(A  + aoff0 + k0), lA0, 16, 0, 0);
            __builtin_amdgcn_global_load_lds((gptr_t)(A  + aoff1 + k0), lA1, 16, 0, 0);
            __builtin_amdgcn_global_load_lds((gptr_t)(pw + boff0 + k0), lB0, 16, 0, 0);
            __builtin_amdgcn_global_load_lds((gptr_t)(pw + boff1 + k0), lB1, 16, 0, 0);
            __syncthreads();

            i32x4 af[4], bf[4];
#pragma unroll
            for (int mi = 0; mi < 4; mi++)
                af[mi] = *(const i32x4*)&As[(wm * 64 + mi * 16 + fr) * 64 + fk];
#pragma unroll
            for (int ni = 0; ni < 4; ni++)
                bf[ni] = *(const i32x4*)&Bs[(wn * 64 + ni * 16 + fr) * 64 + fk];
#pragma unroll
            for (int mi = 0; mi < 4; mi++)
#pragma unroll
                for (int ni = 0; ni < 4; ni++)
                    acc[mi][ni] = __builtin_amdgcn_mfma_i32_16x16x64_i8(
                        af[mi], bf[ni], acc[mi][ni], 0, 0, 0);
            __syncthreads();
        }
    }

    const float scale = 1.f / 67108864.f;
    const int cc = lane & 15;
    const int cr = (lane >> 4) * 4;
#pragma unroll
    for (int ni = 0; ni < 4; ni++) {
        const int gc = bn + wn * 64 + ni * 16 + cc;
        const float bv = bias[gc];
#pragma unroll
        for (int mi = 0; mi < 4; mi++) {
            const int gr = bm + wm * 64 + mi * 16 + cr;
            float* cp = C + (size_t)gr * HB_ + gc;
#pragma unroll
            for (int r = 0; r < 4; r++)
                cp[(size_t)r * HB_] = (float)acc[mi][ni][r] * scale + bv;
        }
    }
}

// ---------------- per-(b,h) LIF scans over a time chunk (chunk-local I/O) ----------------
#define SCAN_BODY(SPIKE_STORE)                                                  \
    int idx = blockIdx.x * 256 + threadIdx.x;                                   \
    int b = idx >> 9;                                                           \
    int h = idx & (H_ - 1);                                                     \
    float alpha = 1.f / (1.f + expf(-tau_m[h]));                                \
    float4 tn = ((const float4*)tau_n)[h];                                      \
    float4 beta;                                                                \
    beta.x = 1.f / (1.f + expf(-tn.x));                                         \
    beta.y = 1.f / (1.f + expf(-tn.y));                                         \
    beta.z = 1.f / (1.f + expf(-tn.z));                                         \
    beta.w = 1.f / (1.f + expf(-tn.w));                                         \
    float4 d = ((const float4*)dst)[idx];                                       \
    float m = mst[idx];                                                         \
    float sp = spst[idx];                                                       \
    const float* cp = cur + (size_t)b * tc * HB_ + h * BR_;                     \
    for (int t = 0; t < tc; t++) {                                              \
        float4 c = *(const float4*)cp;                                          \
        cp += HB_;                                                              \
        d.x = beta.x * d.x + (1.f - beta.x) * c.x;                              \
        d.y = beta.y * d.y + (1.f - beta.y) * c.y;                              \
        d.z = beta.z * d.z + (1.f - beta.z) * c.z;                              \
        d.w = beta.w * d.w + (1.f - beta.w) * c.w;                              \
        float s4 = ((d.x + d.y) + d.z) + d.w;                                   \
        m = m * alpha + (1.f - alpha) * s4 - VTH_ * sp;                         \
        sp = (m > VTH_) ? 1.f : 0.f;                                            \
        SPIKE_STORE;                                                            \
    }                                                                           \
    ((float4*)dst)[idx] = d;                                                    \
    mst[idx] = m;                                                               \
    spst[idx] = sp;

__global__ __launch_bounds__(256)
void scan_i8_kernel(const float* __restrict__ cur, float* __restrict__ dst,
                    float* __restrict__ mst, float* __restrict__ spst,
                    int8_t* __restrict__ sout, const float* __restrict__ tau_m,
                    const float* __restrict__ tau_n, int tc) {
    SCAN_BODY(sout[((size_t)b * tc + t) * H_ + h] = (int8_t)(m > VTH_))
}

__global__ __launch_bounds__(256)
void scan_f16_kernel(const float* __restrict__ cur, float* __restrict__ dst,
                     float* __restrict__ mst, float* __restrict__ spst,
                     _Float16* __restrict__ sout, const float* __restrict__ tau_m,
                     const float* __restrict__ tau_n, int tc) {
    SCAN_BODY(sout[((size_t)b * tc + t) * H_ + h] = (_Float16)sp)
}

// ---------------- readout GEMM (MFMA): curo[b,t,o] = s2c[r,:] . (wo0+wo1)[o,:] + bo[o] ----------------
// 128 rows/block, N=32 (20 used), K=512; 2 fp16 planes for fp32-class accuracy
__global__ __launch_bounds__(256)
void rdot_mfma_kernel(const _Float16* __restrict__ s2c, const _Float16* __restrict__ wo0,
                      const _Float16* __restrict__ wo1, const float* __restrict__ bo,
                      float* __restrict__ curo, int t0, int tc) {
    __shared__ alignas(16) _Float16 As[128 * 32];   // 8 KB
    __shared__ alignas(16) _Float16 B0s[32 * 32];   // 2 KB
    __shared__ alignas(16) _Float16 B1s[32 * 32];
    const int tid  = threadIdx.x;
    const int wave = tid >> 6, lane = tid & 63;
    const int bm = blockIdx.x * 128;

    const int    srow  = tid >> 2;
    const int    skoff = (tid & 3) * 8;
    const size_t aoff0 = (size_t)(bm + srow) * H_ + skoff;
    const size_t aoff1 = aoff0 + (size_t)64 * H_;
    lptr_t lA0 = (lptr_t)(As + wave * 512);
    lptr_t lA1 = (lptr_t)(As + 2048 + wave * 512);
    // B staging: waves 0/1 -> plane0 halves, waves 2/3 -> plane1 halves
    const _Float16* bsrc = (wave < 2) ? wo0 : wo1;
    const int bw = wave & 1;                        // half index within plane
    const size_t boff = (size_t)(bw * 16 + (lane >> 2)) * H_ + (lane & 3) * 8;
    lptr_t lB = (lptr_t)(((wave < 2) ? B0s : B1s) + bw * 512);

    const int fr = lane & 15;
    const int fk = (lane >> 4) * 8;

    f32x4 acc[2][2] = {};

    for (int kt = 0; kt < H_ / 32; kt++) {
        const int k0 = kt * 32;
        __builtin_amdgcn_global_load_lds((gptr_t)(s2c + aoff0 + k0), lA0, 16, 0, 0);
        __builtin_amdgcn_global_load_lds((gptr_t)(s2c + aoff1 + k0), lA1, 16, 0, 0);
        __builtin_amdgcn_global_load_lds((gptr_t)(bsrc + boff + k0), lB, 16, 0, 0);
        __syncthreads();

        half8 af[2], b0[2], b1[2];
#pragma unroll
        for (int mi = 0; mi < 2; mi++)
            af[mi] = *(const half8*)&As[(wave * 32 + mi * 16 + fr) * 32 + fk];
#pragma unroll
        for (int ni = 0; ni < 2; ni++) {
            b0[ni] = *(const half8*)&B0s[(ni * 16 + fr) * 32 + fk];
            b1[ni] = *(const half8*)&B1s[(ni * 16 + fr) * 32 + fk];
        }
#pragma unroll
        for (int mi = 0; mi < 2; mi++)
#pragma unroll
            for (int ni = 0; ni < 2; ni++) {
                acc[mi][ni] = __builtin_amdgcn_mfma_f32_16x16x32_f16(af[mi], b0[ni], acc[mi][ni], 0, 0, 0);
                acc[mi][ni] = __builtin_amdgcn_mfma_f32_16x16x32_f16(af[mi], b1[ni], acc[mi][ni], 0, 0, 0);
            }
        __syncthreads();
    }

    const int cc = lane & 15;
    const int cr = (lane >> 4) * 4;
#pragma unroll
    for (int ni = 0; ni < 2; ni++) {
        const int gc = ni * 16 + cc;
        if (gc < OUT_) {
            const float bv = bo[gc];
#pragma unroll
            for (int mi = 0; mi < 2; mi++) {
#pragma unroll
                for (int r = 0; r < 4; r++) {
                    const int gr = bm + wave * 32 + mi * 16 + cr + r;
                    const int bb = gr / tc, tl = gr - bb * tc;
                    curo[((size_t)bb * T_ + t0 + tl) * OUT_ + gc] = acc[mi][ni][r] + bv;
                }
            }
        }
    }
}

// ---------------- parallel readout: segmented scan + t-parallel softmax-sum ----------------
#define RT_SEG 12
#define RT_LEN 21   // 12*21 = 252 >= 250

__global__ __launch_bounds__(256)
void readout_kernel(const float* __restrict__ curo, const float* __restrict__ tau_mo,
                    float* __restrict__ out) {
    __shared__ float moS[T_ * OUT_];          // 20 KB
    __shared__ float segA[RT_SEG][OUT_];
    __shared__ float segU[RT_SEG][OUT_];
    __shared__ float pre[RT_SEG][OUT_];
    __shared__ float accS[OUT_];
    const int b = blockIdx.x;
    const int tid = threadIdx.x;
    const float* cb = curo + (size_t)b * T_ * OUT_;

    const int o = tid % OUT_;
    const int sg = tid / OUT_;
    const float ao = 1.f / (1.f + expf(-tau_mo[o]));

    if (tid < RT_SEG * OUT_) {
        int t0 = sg * RT_LEN;
        int t1 = min(T_, t0 + RT_LEN);
        float u = 0.f, Ap = 1.f;
        for (int t = t0; t < t1; t++) {
            u = ao * u + (1.f - ao) * cb[t * OUT_ + o];
            Ap *= ao;
        }
        segU[sg][o] = u; segA[sg][o] = Ap;
    }
    if (tid < OUT_) accS[tid] = 0.f;
    __syncthreads();
    if (tid < OUT_) {
        float m = 0.f;
        for (int s = 0; s < RT_SEG; s++) {
            pre[s][tid] = m;
            m = segA[s][tid] * m + segU[s][tid];
        }
    }
    __syncthreads();
    if (tid < RT_SEG * OUT_) {
        int t0 = sg * RT_LEN;
        int t1 = min(T_, t0 + RT_LEN);
        float m = pre[sg][o];
        for (int t = t0; t < t1; t++) {
            m = ao * m + (1.f - ao) * cb[t * OUT_ + o];
            moS[t * OUT_ + o] = m;
        }
    }
    __syncthreads();
    if (tid >= WARM_ + 1 && tid < T_) {
        int t = tid;
        float mx = -3.0e38f;
#pragma unroll
        for (int o2 = 0; o2 < OUT_; o2++) mx = fmaxf(mx, moS[t * OUT_ + o2]);
        float es[OUT_]; float se = 0.f;
#pragma unroll
        for (int o2 = 0; o2 < OUT_; o2++) {
            float e = expf(moS[t * OUT_ + o2] - mx);
            es[o2] = e; se += e;
        }
        float inv = 1.f / se;
#pragma unroll
        for (int o2 = 0; o2 < OUT_; o2++) atomicAdd(&accS[o2], es[o2] * inv);
    }
    __syncthreads();
    if (tid < OUT_) out[(size_t)b * OUT_ + tid] = accS[tid];
}

extern "C" void kernel_launch(void* const* d_in, const int* in_sizes, int n_in,
                              void* d_out, int out_size, void* d_ws, size_t ws_size,
                              hipStream_t stream) {
    const float* x      = (const float*)d_in[0];
    const float* W1     = (const float*)d_in[1];
    const float* b1     = (const float*)d_in[2];
    const float* tau_m1 = (const float*)d_in[3];
    const float* tau_n1 = (const float*)d_in[4];
    const float* mask1  = (const float*)d_in[5];
    const float* W2     = (const float*)d_in[6];
    const float* b2     = (const float*)d_in[7];
    const float* tau_m2 = (const float*)d_in[8];
    const float* tau_n2 = (const float*)d_in[9];
    const float* mask2  = (const float*)d_in[10];
    const float* Wo     = (const float*)d_in[11];
    const float* bo     = (const float*)d_in[12];
    const float* tau_mo = (const float*)d_in[13];
    float* out = (float*)d_out;

    // ws_size-adaptive chunking: per-tc cost = 1605632 B/step + ~17 MB fixed
    const size_t fixedB = (size_t)18 * 1024 * 1024;
    int ncs;  int tcs[3];
    if (ws_size >= fixedB + (size_t)250 * 1605632) { ncs = 1; tcs[0] = 250; }
    else if (ws_size >= fixedB + (size_t)125 * 1605632) { ncs = 2; tcs[0] = tcs[1] = 125; }
    else { ncs = 3; tcs[0] = 100; tcs[1] = 100; tcs[2] = 50; }
    const int tcm = tcs[0];   // max chunk

    char* p = (char*)d_ws;
    auto alloc = [&](size_t bytes) { char* r = p; p += (bytes + 255) & ~(size_t)255; return r; };
    _Float16* w10 = (_Float16*)alloc((size_t)HB_ * INP_ * 2);
    _Float16* w11 = (_Float16*)alloc((size_t)HB_ * INP_ * 2);
    int8_t*   q2  = (int8_t*)alloc((size_t)HB_ * H_);
    int8_t*   q1  = (int8_t*)alloc((size_t)HB_ * H_);
    int8_t*   q0  = (int8_t*)alloc((size_t)HB_ * H_);
    _Float16* wo0 = (_Float16*)alloc((size_t)32 * H_ * 2);
    _Float16* wo1 = (_Float16*)alloc((size_t)32 * H_ * 2);
    _Float16* xc0 = (_Float16*)alloc((size_t)B_ * tcm * INP_ * 2);
    _Float16* xc1 = (_Float16*)alloc((size_t)B_ * tcm * INP_ * 2);
    int8_t*   s1c = (int8_t*)alloc((size_t)B_ * tcm * H_);
    _Float16* s2c = (_Float16*)alloc((size_t)B_ * tcm * H_ * 2);
    float* cur    = (float*)alloc((size_t)B_ * tcm * HB_ * 4);
    float* curo   = (float*)alloc((size_t)B_ * T_ * OUT_ * 4);
    float* st     = (float*)alloc((size_t)786432 * 4);
    float* d1  = st;
    float* m1  = d1 + (size_t)B_ * H_ * BR_;
    float* sp1 = m1 + (size_t)B_ * H_;
    float* d2  = sp1 + (size_t)B_ * H_;
    float* m2  = d2 + (size_t)B_ * H_ * BR_;
    float* sp2 = m2 + (size_t)B_ * H_;

    w1prep_kernel<<<(HB_ * INP_ + 255) / 256, 256, 0, stream>>>(W1, mask1, w10, w11);
    w2prep_kernel<<<(HB_ * H_ + 255) / 256, 256, 0, stream>>>(W2, mask2, q2, q1, q0);
    woprep_kernel<<<(32 * H_ + 255) / 256, 256, 0, stream>>>(Wo, wo0, wo1);
    zero_kernel<<<(786432 / 4 + 255) / 256, 256, 0, stream>>>(st, 786432 / 4);

    int t0 = 0;
    for (int c = 0; c < ncs; c++) {
        const int tc = tcs[c];
        const int M = B_ * tc;                 // multiple of 128; M/128 == tc
        dim3 gg(tc, HB_ / 128);                // m-fastest: x = m-tile, y = n-tile
        convx_kernel<<<(M * INP_ + 255) / 256, 256, 0, stream>>>(x, xc0, xc1, t0, tc, M * INP_);
        l1_gemm_kernel<<<gg, 256, 0, stream>>>(xc0, xc1, w10, w11, b1, cur);
        scan_i8_kernel<<<B_ * H_ / 256, 256, 0, stream>>>(cur, d1, m1, sp1, s1c, tau_m1, tau_n1, tc);
        mfma_i8_gemm_kernel<<<gg, 256, 0, stream>>>(s1c, q2, q1, q0, b2, cur);
        scan_f16_kernel<<<B_ * H_ / 256, 256, 0, stream>>>(cur, d2, m2, sp2, s2c, tau_m2, tau_n2, tc);
        rdot_mfma_kernel<<<tc, 256, 0, stream>>>(s2c, wo0, wo1, bo, curo, t0, tc);
        t0 += tc;
    }
    readout_kernel<<<B_, 256, 0, stream>>>(curo, tau_mo, out);
}

// Round 7
// 851.813 us; speedup vs baseline: 2.8866x; 1.0865x over previous
//
#include <hip/hip_runtime.h>
#include <math.h>
#include <stdint.h>

// Problem dims
#define B_    128
#define T_    250
#define IN_   700
#define INP_  704    // padded to 32
#define H_    512
#define OUT_  20
#define BR_   4
#define HB_   2048   // H_*BR_
#define WARM_ 10
#define VTH_  1.0f

typedef __attribute__((ext_vector_type(8)))  _Float16 half8;
typedef __attribute__((ext_vector_type(4)))  float f32x4;
typedef __attribute__((ext_vector_type(16))) float f32x16;
typedef __attribute__((ext_vector_type(4)))  int i32x4;
typedef __attribute__((ext_vector_type(16))) int i32x16;
typedef const __attribute__((address_space(1))) void* gptr_t;
typedef __attribute__((address_space(3))) void* lptr_t;

// ---------------- prep: split fp32 -> hi/lo fp16 planes (layer 1) ----------------
__global__ __launch_bounds__(256)
void w1prep_kernel(const float* __restrict__ W, const float* __restrict__ M,
                   _Float16* __restrict__ w0, _Float16* __restrict__ w1) {
    int i = blockIdx.x * 256 + threadIdx.x;           // over HB_*INP_
    if (i >= HB_ * INP_) return;
    int r = i / INP_, c = i - r * INP_;
    float v = (c < IN_) ? W[(size_t)r * IN_ + c] * M[(size_t)r * IN_ + c] : 0.f;
    _Float16 h0 = (_Float16)v;
    w0[i] = h0;
    w1[i] = (_Float16)(v - (float)h0);
}

// ---------------- prep: layer-2 weights -> 3 signed radix-256 i8 planes, scale 2^26 ----------------
__global__ __launch_bounds__(256)
void w2prep_kernel(const float* __restrict__ W, const float* __restrict__ M,
                   int8_t* __restrict__ p2, int8_t* __restrict__ p1,
                   int8_t* __restrict__ p0) {
    int i = blockIdx.x * 256 + threadIdx.x;           // over HB_*H_
    if (i >= HB_ * H_) return;
    float v = W[i] * M[i];
    int q = (int)lrintf(v * 67108864.f);              // |q| <= ~2.97e6
    int b0 = (int)(int8_t)(q & 0xFF);  q = (q - b0) >> 8;
    int b1 = (int)(int8_t)(q & 0xFF);  int b2 = (q - b1) >> 8;   // |b2| <= 46
    p0[i] = (int8_t)b0; p1[i] = (int8_t)b1; p2[i] = (int8_t)b2;
}

// ---------------- prep: readout weights -> hi/lo fp16 planes, n padded to 32 ----------------
__global__ __launch_bounds__(256)
void woprep_kernel(const float* __restrict__ Wo, _Float16* __restrict__ wo0,
                   _Float16* __restrict__ wo1) {
    int i = blockIdx.x * 256 + threadIdx.x;           // over 32*H_
    if (i >= 32 * H_) return;
    int n = i >> 9;
    float v = (n < OUT_) ? Wo[(size_t)n * H_ + (i & (H_ - 1))] : 0.f;
    _Float16 h0 = (_Float16)v;
    wo0[i] = h0;
    wo1[i] = (_Float16)(v - (float)h0);
}

// per-chunk x conversion: global rows (bb*T_+t0+tl) -> chunk-local [128*tc, INP_]
__global__ __launch_bounds__(256)
void convx_kernel(const float* __restrict__ x, _Float16* __restrict__ x0,
                  _Float16* __restrict__ x1, int t0, int tc, int ntot) {
    int i = blockIdx.x * 256 + threadIdx.x;
    if (i >= ntot) return;
    int r = i / INP_, c = i - r * INP_;
    int bb = r / tc, tl = r - bb * tc;
    float v = (c < IN_) ? x[((size_t)bb * T_ + t0 + tl) * IN_ + c] : 0.f;
    _Float16 h0 = (_Float16)v;
    x0[i] = h0;
    x1[i] = (_Float16)(v - (float)h0);
}

__global__ void zero_kernel(float* __restrict__ p, int n4) {
    int i = blockIdx.x * blockDim.x + threadIdx.x;
    if (i < n4) ((float4*)p)[i] = make_float4(0.f, 0.f, 0.f, 0.f);
}

// ---------------- L1 GEMM: 32x32x16 f16 MFMA, 3 products (x0w0 + x0w1 + x1w0) ----------------
// grid (HB_/128, M/128), n-fastest: bn = blockIdx.x, bm = blockIdx.y
__global__ __launch_bounds__(256)
void l1_gemm_kernel(const _Float16* __restrict__ x0, const _Float16* __restrict__ x1,
                    const _Float16* __restrict__ w0, const _Float16* __restrict__ w1,
                    const float* __restrict__ bias, float* __restrict__ C) {
    __shared__ alignas(16) _Float16 A0s[128 * 32];
    __shared__ alignas(16) _Float16 A1s[128 * 32];
    __shared__ alignas(16) _Float16 B0s[128 * 32];
    __shared__ alignas(16) _Float16 B1s[128 * 32];
    const int tid  = threadIdx.x;
    const int wave = tid >> 6, lane = tid & 63;
    const int bm = blockIdx.y * 128, bn = blockIdx.x * 128;

    const int    srow  = tid >> 2;
    const int    skoff = (tid & 3) * 8;
    const size_t aoff0 = (size_t)(bm + srow) * INP_ + skoff;
    const size_t aoff1 = aoff0 + (size_t)64 * INP_;
    const size_t boff0 = (size_t)(bn + srow) * INP_ + skoff;
    const size_t boff1 = boff0 + (size_t)64 * INP_;
    const int lo0 = wave * 512, lo1 = 2048 + wave * 512;

    const int wm = wave & 1, wn = wave >> 1;
    const int row = lane & 31;           // row/col within 32-tile
    const int kh  = (lane >> 5) * 8;     // k-offset (halfs) within 16-K step

    f32x16 acc[2][2] = {};

    for (int kt = 0; kt < INP_ / 32; kt++) {
        const int k0 = kt * 32;
        __builtin_amdgcn_global_load_lds((gptr_t)(x0 + aoff0 + k0), (lptr_t)(A0s + lo0), 16, 0, 0);
        __builtin_amdgcn_global_load_lds((gptr_t)(x0 + aoff1 + k0), (lptr_t)(A0s + lo1), 16, 0, 0);
        __builtin_amdgcn_global_load_lds((gptr_t)(x1 + aoff0 + k0), (lptr_t)(A1s + lo0), 16, 0, 0);
        __builtin_amdgcn_global_load_lds((gptr_t)(x1 + aoff1 + k0), (lptr_t)(A1s + lo1), 16, 0, 0);
        __builtin_amdgcn_global_load_lds((gptr_t)(w0 + boff0 + k0), (lptr_t)(B0s + lo0), 16, 0, 0);
        __builtin_amdgcn_global_load_lds((gptr_t)(w0 + boff1 + k0), (lptr_t)(B0s + lo1), 16, 0, 0);
        __builtin_amdgcn_global_load_lds((gptr_t)(w1 + boff0 + k0), (lptr_t)(B1s + lo0), 16, 0, 0);
        __builtin_amdgcn_global_load_lds((gptr_t)(w1 + boff1 + k0), (lptr_t)(B1s + lo1), 16, 0, 0);
        __syncthreads();

        half8 a0f[2][2], a1f[2][2], b0f[2][2], b1f[2][2];   // [tile][kstep]
#pragma unroll
        for (int mt = 0; mt < 2; mt++)
#pragma unroll
            for (int ks = 0; ks < 2; ks++)
                a0f[mt][ks] = *(const half8*)&A0s[(wm * 64 + mt * 32 + row) * 32 + ks * 16 + kh];
#pragma unroll
        for (int nt = 0; nt < 2; nt++)
#pragma unroll
            for (int ks = 0; ks < 2; ks++)
                b0f[nt][ks] = *(const half8*)&B0s[(wn * 64 + nt * 32 + row) * 32 + ks * 16 + kh];
#pragma unroll
        for (int ks = 0; ks < 2; ks++)
#pragma unroll
            for (int mt = 0; mt < 2; mt++)
#pragma unroll
                for (int nt = 0; nt < 2; nt++)
                    acc[mt][nt] = __builtin_amdgcn_mfma_f32_32x32x16_f16(
                        a0f[mt][ks], b0f[nt][ks], acc[mt][nt], 0, 0, 0);
#pragma unroll
        for (int nt = 0; nt < 2; nt++)
#pragma unroll
            for (int ks = 0; ks < 2; ks++)
                b1f[nt][ks] = *(const half8*)&B1s[(wn * 64 + nt * 32 + row) * 32 + ks * 16 + kh];
#pragma unroll
        for (int ks = 0; ks < 2; ks++)
#pragma unroll
            for (int mt = 0; mt < 2; mt++)
#pragma unroll
                for (int nt = 0; nt < 2; nt++)
                    acc[mt][nt] = __builtin_amdgcn_mfma_f32_32x32x16_f16(
                        a0f[mt][ks], b1f[nt][ks], acc[mt][nt], 0, 0, 0);
#pragma unroll
        for (int mt = 0; mt < 2; mt++)
#pragma unroll
            for (int ks = 0; ks < 2; ks++)
                a1f[mt][ks] = *(const half8*)&A1s[(wm * 64 + mt * 32 + row) * 32 + ks * 16 + kh];
#pragma unroll
        for (int ks = 0; ks < 2; ks++)
#pragma unroll
            for (int mt = 0; mt < 2; mt++)
#pragma unroll
                for (int nt = 0; nt < 2; nt++)
                    acc[mt][nt] = __builtin_amdgcn_mfma_f32_32x32x16_f16(
                        a1f[mt][ks], b0f[nt][ks], acc[mt][nt], 0, 0, 0);
        __syncthreads();
    }

    // C/D: col=lane&31, row=(reg&3)+8*(reg>>2)+4*(lane>>5)
    const int col = lane & 31;
    const int rb  = 4 * (lane >> 5);
#pragma unroll
    for (int nt = 0; nt < 2; nt++) {
        const int gc = bn + wn * 64 + nt * 32 + col;
        const float bv = bias[gc];
#pragma unroll
        for (int mt = 0; mt < 2; mt++) {
#pragma unroll
            for (int reg = 0; reg < 16; reg++) {
                const int gr = bm + wm * 64 + mt * 32 + (reg & 3) + 8 * (reg >> 2) + rb;
                C[(size_t)gr * HB_ + gc] = acc[mt][nt][reg] + bv;
            }
        }
    }
}

// ---------------- i8 fixed-point MFMA GEMM (layer 2): 32x32x32, exact Horner over 3 planes ----------------
__global__ __launch_bounds__(256)
void mfma_i8_gemm_kernel(const int8_t* __restrict__ A,
                         const int8_t* __restrict__ p2, const int8_t* __restrict__ p1,
                         const int8_t* __restrict__ p0,
                         const float* __restrict__ bias, float* __restrict__ C) {
    __shared__ alignas(16) int8_t As[128 * 64];   // 8 KB, K-tile 64
    __shared__ alignas(16) int8_t Bs[128 * 64];
    const int tid  = threadIdx.x;
    const int wave = tid >> 6, lane = tid & 63;
    const int bm = blockIdx.y * 128, bn = blockIdx.x * 128;   // n-fastest

    const int    srow  = tid >> 2;
    const int    skoff = (tid & 3) * 16;
    const size_t aoff0 = (size_t)(bm + srow) * H_ + skoff;
    const size_t aoff1 = aoff0 + (size_t)64 * H_;
    const size_t boff0 = (size_t)(bn + srow) * H_ + skoff;
    const size_t boff1 = boff0 + (size_t)64 * H_;
    lptr_t lA0 = (lptr_t)(As + wave * 1024);
    lptr_t lA1 = (lptr_t)(As + 4096 + wave * 1024);
    lptr_t lB0 = (lptr_t)(Bs + wave * 1024);
    lptr_t lB1 = (lptr_t)(Bs + 4096 + wave * 1024);

    const int wm = wave & 1, wn = wave >> 1;
    const int row = lane & 31;
    const int kb  = (lane >> 5) * 16;   // byte offset within 32-K step

    const int8_t* planes[3] = {p2, p1, p0};
    i32x16 acc[2][2] = {};

#pragma unroll
    for (int s = 0; s < 3; s++) {
        if (s) {
#pragma unroll
            for (int mt = 0; mt < 2; mt++)
#pragma unroll
                for (int nt = 0; nt < 2; nt++) acc[mt][nt] *= 256;  // exact, |acc|<1.6e9
        }
        const int8_t* pw = planes[s];
        for (int kt = 0; kt < H_ / 64; kt++) {
            const int k0 = kt * 64;
            __builtin_amdgcn_global_load_lds((gptr_t)(A  + aoff0 + k0), lA0, 16, 0, 0);
            __builtin_amdgcn_global_load_lds((gptr_t)(A  + aoff1 + k0), lA1, 16, 0, 0);
            __builtin_amdgcn_global_load_lds((gptr_t)(pw + boff0 + k0), lB0, 16, 0, 0);
            __builtin_amdgcn_global_load_lds((gptr_t)(pw + boff1 + k0), lB1, 16, 0, 0);
            __syncthreads();

            i32x4 af[2][2], bf[2][2];
#pragma unroll
            for (int mt = 0; mt < 2; mt++)
#pragma unroll
                for (int ks = 0; ks < 2; ks++)
                    af[mt][ks] = *(const i32x4*)&As[(wm * 64 + mt * 32 + row) * 64 + ks * 32 + kb];
#pragma unroll
            for (int nt = 0; nt < 2; nt++)
#pragma unroll
                for (int ks = 0; ks < 2; ks++)
                    bf[nt][ks] = *(const i32x4*)&Bs[(wn * 64 + nt * 32 + row) * 64 + ks * 32 + kb];
#pragma unroll
            for (int ks = 0; ks < 2; ks++)
#pragma unroll
                for (int mt = 0; mt < 2; mt++)
#pragma unroll
                    for (int nt = 0; nt < 2; nt++)
                        acc[mt][nt] = __builtin_amdgcn_mfma_i32_32x32x32_i8(
                            af[mt][ks], bf[nt][ks], acc[mt][nt], 0, 0, 0);
            __syncthreads();
        }
    }

    const float scale = 1.f / 67108864.f;
    const int col = lane & 31;
    const int rb  = 4 * (lane >> 5);
#pragma unroll
    for (int nt = 0; nt < 2; nt++) {
        const int gc = bn + wn * 64 + nt * 32 + col;
        const float bv = bias[gc];
#pragma unroll
        for (int mt = 0; mt < 2; mt++) {
#pragma unroll
            for (int reg = 0; reg < 16; reg++) {
                const int gr = bm + wm * 64 + mt * 32 + (reg & 3) + 8 * (reg >> 2) + rb;
                C[(size_t)gr * HB_ + gc] = (float)acc[mt][nt][reg] * scale + bv;
            }
        }
    }
}

// ---------------- per-(b,h) LIF scans over a time chunk (chunk-local I/O) ----------------
#define SCAN_BODY(SPIKE_STORE)                                                  \
    int idx = blockIdx.x * 256 + threadIdx.x;                                   \
    int b = idx >> 9;                                                           \
    int h = idx & (H_ - 1);                                                     \
    float alpha = 1.f / (1.f + expf(-tau_m[h]));                                \
    float4 tn = ((const float4*)tau_n)[h];                                      \
    float4 beta;                                                                \
    beta.x = 1.f / (1.f + expf(-tn.x));                                         \
    beta.y = 1.f / (1.f + expf(-tn.y));                                         \
    beta.z = 1.f / (1.f + expf(-tn.z));                                         \
    beta.w = 1.f / (1.f + expf(-tn.w));                                         \
    float4 d = ((const float4*)dst)[idx];                                       \
    float m = mst[idx];                                                         \
    float sp = spst[idx];                                                       \
    const float* cp = cur + (size_t)b * tc * HB_ + h * BR_;                     \
    for (int t = 0; t < tc; t++) {                                              \
        float4 c = *(const float4*)cp;                                          \
        cp += HB_;                                                              \
        d.x = beta.x * d.x + (1.f - beta.x) * c.x;                              \
        d.y = beta.y * d.y + (1.f - beta.y) * c.y;                              \
        d.z = beta.z * d.z + (1.f - beta.z) * c.z;                              \
        d.w = beta.w * d.w + (1.f - beta.w) * c.w;                              \
        float s4 = ((d.x + d.y) + d.z) + d.w;                                   \
        m = m * alpha + (1.f - alpha) * s4 - VTH_ * sp;                         \
        sp = (m > VTH_) ? 1.f : 0.f;                                            \
        SPIKE_STORE;                                                            \
    }                                                                           \
    ((float4*)dst)[idx] = d;                                                    \
    mst[idx] = m;                                                               \
    spst[idx] = sp;

__global__ __launch_bounds__(256)
void scan_i8_kernel(const float* __restrict__ cur, float* __restrict__ dst,
                    float* __restrict__ mst, float* __restrict__ spst,
                    int8_t* __restrict__ sout, const float* __restrict__ tau_m,
                    const float* __restrict__ tau_n, int tc) {
    SCAN_BODY(sout[((size_t)b * tc + t) * H_ + h] = (int8_t)(m > VTH_))
}

__global__ __launch_bounds__(256)
void scan_f16_kernel(const float* __restrict__ cur, float* __restrict__ dst,
                     float* __restrict__ mst, float* __restrict__ spst,
                     _Float16* __restrict__ sout, const float* __restrict__ tau_m,
                     const float* __restrict__ tau_n, int tc) {
    SCAN_BODY(sout[((size_t)b * tc + t) * H_ + h] = (_Float16)sp)
}

// ---------------- readout GEMM (MFMA 16x16): curo[b,t,o] = s2c . (wo0+wo1)^T + bo ----------------
__global__ __launch_bounds__(256)
void rdot_mfma_kernel(const _Float16* __restrict__ s2c, const _Float16* __restrict__ wo0,
                      const _Float16* __restrict__ wo1, const float* __restrict__ bo,
                      float* __restrict__ curo, int t0, int tc) {
    __shared__ alignas(16) _Float16 As[128 * 32];   // 8 KB
    __shared__ alignas(16) _Float16 B0s[32 * 32];   // 2 KB
    __shared__ alignas(16) _Float16 B1s[32 * 32];
    const int tid  = threadIdx.x;
    const int wave = tid >> 6, lane = tid & 63;
    const int bm = blockIdx.x * 128;

    const int    srow  = tid >> 2;
    const int    skoff = (tid & 3) * 8;
    const size_t aoff0 = (size_t)(bm + srow) * H_ + skoff;
    const size_t aoff1 = aoff0 + (size_t)64 * H_;
    lptr_t lA0 = (lptr_t)(As + wave * 512);
    lptr_t lA1 = (lptr_t)(As + 2048 + wave * 512);
    const _Float16* bsrc = (wave < 2) ? wo0 : wo1;
    const int bw = wave & 1;
    const size_t boff = (size_t)(bw * 16 + (lane >> 2)) * H_ + (lane & 3) * 8;
    lptr_t lB = (lptr_t)(((wave < 2) ? B0s : B1s) + bw * 512);

    const int fr = lane & 15;
    const int fk = (lane >> 4) * 8;

    f32x4 acc[2][2] = {};

    for (int kt = 0; kt < H_ / 32; kt++) {
        const int k0 = kt * 32;
        __builtin_amdgcn_global_load_lds((gptr_t)(s2c + aoff0 + k0), lA0, 16, 0, 0);
        __builtin_amdgcn_global_load_lds((gptr_t)(s2c + aoff1 + k0), lA1, 16, 0, 0);
        __builtin_amdgcn_global_load_lds((gptr_t)(bsrc + boff + k0), lB, 16, 0, 0);
        __syncthreads();

        half8 af[2], b0[2], b1[2];
#pragma unroll
        for (int mi = 0; mi < 2; mi++)
            af[mi] = *(const half8*)&As[(wave * 32 + mi * 16 + fr) * 32 + fk];
#pragma unroll
        for (int ni = 0; ni < 2; ni++) {
            b0[ni] = *(const half8*)&B0s[(ni * 16 + fr) * 32 + fk];
            b1[ni] = *(const half8*)&B1s[(ni * 16 + fr) * 32 + fk];
        }
#pragma unroll
        for (int mi = 0; mi < 2; mi++)
#pragma unroll
            for (int ni = 0; ni < 2; ni++) {
                acc[mi][ni] = __builtin_amdgcn_mfma_f32_16x16x32_f16(af[mi], b0[ni], acc[mi][ni], 0, 0, 0);
                acc[mi][ni] = __builtin_amdgcn_mfma_f32_16x16x32_f16(af[mi], b1[ni], acc[mi][ni], 0, 0, 0);
            }
        __syncthreads();
    }

    const int cc = lane & 15;
    const int cr = (lane >> 4) * 4;
#pragma unroll
    for (int ni = 0; ni < 2; ni++) {
        const int gc = ni * 16 + cc;
        if (gc < OUT_) {
            const float bv = bo[gc];
#pragma unroll
            for (int mi = 0; mi < 2; mi++) {
#pragma unroll
                for (int r = 0; r < 4; r++) {
                    const int gr = bm + wave * 32 + mi * 16 + cr + r;
                    const int bb = gr / tc, tl = gr - bb * tc;
                    curo[((size_t)bb * T_ + t0 + tl) * OUT_ + gc] = acc[mi][ni][r] + bv;
                }
            }
        }
    }
}

// ---------------- parallel readout: segmented scan + t-parallel softmax-sum ----------------
#define RT_SEG 12
#define RT_LEN 21   // 12*21 = 252 >= 250

__global__ __launch_bounds__(256)
void readout_kernel(const float* __restrict__ curo, const float* __restrict__ tau_mo,
                    float* __restrict__ out) {
    __shared__ float moS[T_ * OUT_];          // 20 KB
    __shared__ float segA[RT_SEG][OUT_];
    __shared__ float segU[RT_SEG][OUT_];
    __shared__ float pre[RT_SEG][OUT_];
    __shared__ float accS[OUT_];
    const int b = blockIdx.x;
    const int tid = threadIdx.x;
    const float* cb = curo + (size_t)b * T_ * OUT_;

    const int o = tid % OUT_;
    const int sg = tid / OUT_;
    const float ao = 1.f / (1.f + expf(-tau_mo[o]));

    if (tid < RT_SEG * OUT_) {
        int t0 = sg * RT_LEN;
        int t1 = min(T_, t0 + RT_LEN);
        float u = 0.f, Ap = 1.f;
        for (int t = t0; t < t1; t++) {
            u = ao * u + (1.f - ao) * cb[t * OUT_ + o];
            Ap *= ao;
        }
        segU[sg][o] = u; segA[sg][o] = Ap;
    }
    if (tid < OUT_) accS[tid] = 0.f;
    __syncthreads();
    if (tid < OUT_) {
        float m = 0.f;
        for (int s = 0; s < RT_SEG; s++) {
            pre[s][tid] = m;
            m = segA[s][tid] * m + segU[s][tid];
        }
    }
    __syncthreads();
    if (tid < RT_SEG * OUT_) {
        int t0 = sg * RT_LEN;
        int t1 = min(T_, t0 + RT_LEN);
        float m = pre[sg][o];
        for (int t = t0; t < t1; t++) {
            m = ao * m + (1.f - ao) * cb[t * OUT_ + o];
            moS[t * OUT_ + o] = m;
        }
    }
    __syncthreads();
    if (tid >= WARM_ + 1 && tid < T_) {
        int t = tid;
        float mx = -3.0e38f;
#pragma unroll
        for (int o2 = 0; o2 < OUT_; o2++) mx = fmaxf(mx, moS[t * OUT_ + o2]);
        float es[OUT_]; float se = 0.f;
#pragma unroll
        for (int o2 = 0; o2 < OUT_; o2++) {
            float e = expf(moS[t * OUT_ + o2] - mx);
            es[o2] = e; se += e;
        }
        float inv = 1.f / se;
#pragma unroll
        for (int o2 = 0; o2 < OUT_; o2++) atomicAdd(&accS[o2], es[o2] * inv);
    }
    __syncthreads();
    if (tid < OUT_) out[(size_t)b * OUT_ + tid] = accS[tid];
}

extern "C" void kernel_launch(void* const* d_in, const int* in_sizes, int n_in,
                              void* d_out, int out_size, void* d_ws, size_t ws_size,
                              hipStream_t stream) {
    const float* x      = (const float*)d_in[0];
    const float* W1     = (const float*)d_in[1];
    const float* b1     = (const float*)d_in[2];
    const float* tau_m1 = (const float*)d_in[3];
    const float* tau_n1 = (const float*)d_in[4];
    const float* mask1  = (const float*)d_in[5];
    const float* W2     = (const float*)d_in[6];
    const float* b2     = (const float*)d_in[7];
    const float* tau_m2 = (const float*)d_in[8];
    const float* tau_n2 = (const float*)d_in[9];
    const float* mask2  = (const float*)d_in[10];
    const float* Wo     = (const float*)d_in[11];
    const float* bo     = (const float*)d_in[12];
    const float* tau_mo = (const float*)d_in[13];
    float* out = (float*)d_out;

    // ws-adaptive chunking. Single-chunk footprint ~367 MB (s1c/s2c aliased into xc),
    // 2x125 footprint ~216 MB, 100/100/50 ~176 MB.
    int ncs;  int tcs[3];
    bool single = (ws_size >= (size_t)368000000);
    if (single)                                { ncs = 1; tcs[0] = 250; }
    else if (ws_size >= (size_t)219000000)     { ncs = 2; tcs[0] = tcs[1] = 125; }
    else                                       { ncs = 3; tcs[0] = 100; tcs[1] = 100; tcs[2] = 50; }
    const int tcm = tcs[0];

    char* p = (char*)d_ws;
    auto alloc = [&](size_t bytes) { char* r = p; p += (bytes + 255) & ~(size_t)255; return r; };
    _Float16* w10 = (_Float16*)alloc((size_t)HB_ * INP_ * 2);
    _Float16* w11 = (_Float16*)alloc((size_t)HB_ * INP_ * 2);
    int8_t*   q2  = (int8_t*)alloc((size_t)HB_ * H_);
    int8_t*   q1  = (int8_t*)alloc((size_t)HB_ * H_);
    int8_t*   q0  = (int8_t*)alloc((size_t)HB_ * H_);
    _Float16* wo0 = (_Float16*)alloc((size_t)32 * H_ * 2);
    _Float16* wo1 = (_Float16*)alloc((size_t)32 * H_ * 2);
    _Float16* xc0 = (_Float16*)alloc((size_t)B_ * tcm * INP_ * 2);
    _Float16* xc1 = (_Float16*)alloc((size_t)B_ * tcm * INP_ * 2);
    int8_t*   s1c;
    _Float16* s2c;
    if (single) {  // xc planes are dead after l1_gemm; reuse them for spikes
        s1c = (int8_t*)xc0;        // needs 16 MB <= 45 MB
        s2c = (_Float16*)xc1;      // needs 33 MB <= 45 MB
    } else {
        s1c = (int8_t*)alloc((size_t)B_ * tcm * H_);
        s2c = (_Float16*)alloc((size_t)B_ * tcm * H_ * 2);
    }
    float* cur    = (float*)alloc((size_t)B_ * tcm * HB_ * 4);
    float* curo   = (float*)alloc((size_t)B_ * T_ * OUT_ * 4);
    float* st     = (float*)alloc((size_t)786432 * 4);
    float* d1  = st;
    float* m1  = d1 + (size_t)B_ * H_ * BR_;
    float* sp1 = m1 + (size_t)B_ * H_;
    float* d2  = sp1 + (size_t)B_ * H_;
    float* m2  = d2 + (size_t)B_ * H_ * BR_;
    float* sp2 = m2 + (size_t)B_ * H_;

    w1prep_kernel<<<(HB_ * INP_ + 255) / 256, 256, 0, stream>>>(W1, mask1, w10, w11);
    w2prep_kernel<<<(HB_ * H_ + 255) / 256, 256, 0, stream>>>(W2, mask2, q2, q1, q0);
    woprep_kernel<<<(32 * H_ + 255) / 256, 256, 0, stream>>>(Wo, wo0, wo1);
    zero_kernel<<<(786432 / 4 + 255) / 256, 256, 0, stream>>>(st, 786432 / 4);

    int t0 = 0;
    for (int c = 0; c < ncs; c++) {
        const int tc = tcs[c];
        const int M = B_ * tc;                 // multiple of 128
        dim3 gg(HB_ / 128, M / 128);           // n-fastest: x = n-tile, y = m-tile
        convx_kernel<<<(M * INP_ + 255) / 256, 256, 0, stream>>>(x, xc0, xc1, t0, tc, M * INP_);
        l1_gemm_kernel<<<gg, 256, 0, stream>>>(xc0, xc1, w10, w11, b1, cur);
        scan_i8_kernel<<<B_ * H_ / 256, 256, 0, stream>>>(cur, d1, m1, sp1, s1c, tau_m1, tau_n1, tc);
        mfma_i8_gemm_kernel<<<gg, 256, 0, stream>>>(s1c, q2, q1, q0, b2, cur);
        scan_f16_kernel<<<B_ * H_ / 256, 256, 0, stream>>>(cur, d2, m2, sp2, s2c, tau_m2, tau_n2, tc);
        rdot_mfma_kernel<<<M / 128, 256, 0, stream>>>(s2c, wo0, wo1, bo, curo, t0, tc);
        t0 += tc;
    }
    readout_kernel<<<B_, 256, 0, stream>>>(curo, tau_mo, out);
}